// Round 7
// baseline (1625.171 us; speedup 1.0000x reference)
//
#include <hip/hip_runtime.h>
#include <cstdint>

#define HIDDEN  128
#define NLAYERS 6
#define NNODES  50000
#define NEDGES  640000

typedef short short8 __attribute__((ext_vector_type(8)));
typedef float f32x4  __attribute__((ext_vector_type(4)));
typedef unsigned int   u32x4 __attribute__((ext_vector_type(4)));

// ---- bf16 <-> f32 helpers -------------------------------------------------
__device__ __forceinline__ float bf2f(unsigned short u) {
    return __uint_as_float(((unsigned int)u) << 16);
}
__device__ __forceinline__ unsigned short f2bf(float f) {
    unsigned int u = __float_as_uint(f);
    unsigned int r = u + 0x7FFFu + ((u >> 16) & 1u);
    return (unsigned short)(r >> 16);
}
// HW packed conversion: v_cvt_pk_bf16_f32 (RNE) == f2bf(a) | f2bf(b)<<16.
__device__ __forceinline__ unsigned int pack2(float a, float b) {
    unsigned int r;
    asm("v_cvt_pk_bf16_f32 %0, %1, %2" : "=v"(r) : "v"(a), "v"(b));
    return r;
}
__device__ __forceinline__ void unpack8u(u32x4 v, float* f) {
    f[0] = bf2f((unsigned short)(v.x & 0xffff)); f[1] = bf2f((unsigned short)(v.x >> 16));
    f[2] = bf2f((unsigned short)(v.y & 0xffff)); f[3] = bf2f((unsigned short)(v.y >> 16));
    f[4] = bf2f((unsigned short)(v.z & 0xffff)); f[5] = bf2f((unsigned short)(v.z >> 16));
    f[6] = bf2f((unsigned short)(v.w & 0xffff)); f[7] = bf2f((unsigned short)(v.w >> 16));
}

// ---- barrier that drains ONLY lgkmcnt (LDS); prefetched global loads stay
//      in flight across it. Cross-wave deps here flow through LDS only.
__device__ __forceinline__ void barrier_lgkm() {
    asm volatile("s_waitcnt lgkmcnt(0)" ::: "memory");
    __builtin_amdgcn_s_barrier();
    __builtin_amdgcn_sched_barrier(0);
}

// ---------------------------------------------------------------------------
// Index dtype detection + canonicalization
// ---------------------------------------------------------------------------
__global__ void detect_kernel(const int* __restrict__ ei, int* __restrict__ flag)
{
    int lane = threadIdx.x;
    int v = ei[2 * lane + 1];
    unsigned long long b = __ballot(v != 0);
    if (lane == 0) *flag = (b != 0ULL) ? 1 : 0;
}

__global__ void normidx_kernel(const int* __restrict__ ei, const int* __restrict__ flag,
                               int* __restrict__ s32, int* __restrict__ d32)
{
    int e = blockIdx.x * blockDim.x + threadIdx.x;
    if (e >= NEDGES) return;
    int s, d;
    if (*flag) { s = ei[e]; d = ei[NEDGES + e]; }
    else       { s = ei[2 * e]; d = ei[2 * (NEDGES + e)]; }
    s32[e] = min(max(s, 0), NNODES - 1);
    d32[e] = min(max(d, 0), NNODES - 1);
}

__global__ void degree_kernel(const int* __restrict__ dst, int* __restrict__ deg)
{
    int e = blockIdx.x * blockDim.x + threadIdx.x;
    if (e < NEDGES) atomicAdd(&deg[dst[e]], 1);
}

// ---------------------------------------------------------------------------
// Exclusive scan over deg[0..NNODES) -> off, cursor. One 1024-thread block.
// ---------------------------------------------------------------------------
#define SCAN_T 1024
__global__ void scan_kernel(const int* __restrict__ deg, int* __restrict__ off,
                            int* __restrict__ cursor)
{
    __shared__ int part[SCAN_T];
    const int t = threadIdx.x;
    const int CH = (NNODES + SCAN_T - 1) / SCAN_T;
    const int base = t * CH;
    int s = 0;
    for (int i = 0; i < CH; ++i) {
        int idx = base + i;
        if (idx < NNODES) s += deg[idx];
    }
    part[t] = s;
    __syncthreads();
    for (int d = 1; d < SCAN_T; d <<= 1) {
        int v = (t >= d) ? part[t - d] : 0;
        __syncthreads();
        part[t] += v;
        __syncthreads();
    }
    int run = (t == 0) ? 0 : part[t - 1];
    for (int i = 0; i < CH; ++i) {
        int idx = base + i;
        if (idx < NNODES) {
            off[idx] = run;
            cursor[idx] = run;
            run += deg[idx];
        }
    }
    if (t == SCAN_T - 1) off[NNODES] = run;
}

__global__ void scatter_kernel(const int* __restrict__ s32, const int* __restrict__ d32,
                               int* __restrict__ cursor,
                               int* __restrict__ sp, int* __restrict__ dp, int* __restrict__ ep)
{
    int e = blockIdx.x * blockDim.x + threadIdx.x;
    if (e >= NEDGES) return;
    int d = d32[e];
    int p = atomicAdd(&cursor[d], 1);
    sp[p] = s32[e];
    dp[p] = d;
    ep[p] = e;
}

// ---------------------------------------------------------------------------
// Weight transpose+convert: W [L][K][N] fp32 -> WT [L][N][K] bf16
// ---------------------------------------------------------------------------
__global__ void transpose_kernel(const float* __restrict__ W, unsigned short* __restrict__ WT,
                                 int K, int N, int L)
{
    long idx = (long)blockIdx.x * 256 + threadIdx.x;
    long tot = (long)L * K * N;
    if (idx >= tot) return;
    int kn = (int)(idx % ((long)K * N));
    int l  = (int)(idx / ((long)K * N));
    int k = kn / N;
    int n = kn % N;
    WT[(long)l * K * N + (long)n * K + k] = f2bf(W[idx]);
}

// ---------------------------------------------------------------------------
// Encoder into permuted layout: ef[p] = enc(ea[ep[p]])
// ---------------------------------------------------------------------------
__global__ void encode_kernel(const float* __restrict__ ea,
                              const float* __restrict__ w,
                              const float* __restrict__ b,
                              const int* __restrict__ ep,
                              unsigned short* __restrict__ ef)
{
    int idx = blockIdx.x * blockDim.x + threadIdx.x;
    int p = idx >> 5;
    if (p >= NEDGES) return;
    int e = ep[p];
    int j = (idx & 31) << 2;
    float a0 = ea[e * 3 + 0], a1 = ea[e * 3 + 1], a2 = ea[e * 3 + 2];
    float4 w0 = *(const float4*)(w + 0 * HIDDEN + j);
    float4 w1 = *(const float4*)(w + 1 * HIDDEN + j);
    float4 w2 = *(const float4*)(w + 2 * HIDDEN + j);
    float4 bb = *(const float4*)(b + j);
    ushort4 o;
    o.x = f2bf(fmaf(a0, w0.x, fmaf(a1, w1.x, fmaf(a2, w2.x, bb.x))));
    o.y = f2bf(fmaf(a0, w0.y, fmaf(a1, w1.y, fmaf(a2, w2.y, bb.y))));
    o.z = f2bf(fmaf(a0, w0.z, fmaf(a1, w1.z, fmaf(a2, w2.z, bb.z))));
    o.w = f2bf(fmaf(a0, w0.w, fmaf(a1, w1.w, fmaf(a2, w2.w, bb.w))));
    *(ushort4*)(ef + (long)p * HIDDEN + j) = o;
}

// ---------------------------------------------------------------------------
// MFMA edge layer — 8-WAVE variant (512 threads, same 128-edge tile, same
// 46080 B LDS): 3 blocks/CU x 8 waves = 24 waves/CU (was 12) -> 2x memory-
// level parallelism at identical traffic. Each wave owns a 16-row band.
// A-frags (== ef_old regs) direct from global; B cooperatively LDS-staged.
// ---------------------------------------------------------------------------
__global__ __launch_bounds__(512, 6)
void edge_layer_mfma(const unsigned short* __restrict__ Xa,   // [N][128] bf16
                     const unsigned short* __restrict__ Xb,   // [N][128] bf16
                     unsigned short* __restrict__ ef,
                     float* __restrict__ sums,
                     const int* __restrict__ sp,
                     const int* __restrict__ dp,
                     const unsigned short* __restrict__ W1T,  // [128][384] bf16; W1c at k+256
                     const float* __restrict__ b1,
                     const unsigned short* __restrict__ W2T,  // [128][128] bf16
                     const float* __restrict__ b2)
{
    __shared__ __align__(16) unsigned char buf[45056];
    unsigned short* Hs = (unsigned short*)buf;               // 128 x 136
    unsigned short* Bs = (unsigned short*)(buf + 34816);     // 128 x 40
    __shared__ int dv[128];
    __shared__ int sv[128];

    const int tid = threadIdx.x;
    // XCD-chunked swizzle: grid = 5000 (= 8 x 625). Each XCD gets a contiguous
    // edge (= dst) range -> sums atomic lines stay in its private L2.
    const int nwg = (int)gridDim.x;
    const int bid = (int)blockIdx.x;
    const int sb  = (bid & 7) * (nwg >> 3) + (bid >> 3);
    const long eb = (long)sb * 128;

    if (tid < 128)      dv[tid]       = dp[eb + tid];
    else if (tid < 256) sv[tid - 128] = sp[eb + tid - 128];
    // visibility of dv/sv to all waves: guaranteed by the first barrier_lgkm
    // in the GEMM1 loop (writers drain lgkmcnt before passing it).

    const int lane = tid & 63;
    const int wv   = tid >> 6;       // 0..7 — wave band = rows [wv*16, wv*16+16)
    const int mn   = lane & 15;
    const int q    = lane >> 4;
    const int bn   = tid >> 2;       // 0..127 (B-stage row)
    const int bk   = (tid & 3) << 3; // 0,8,16,24 (shorts)

    // W chunk-0 prefetch FIRST so its vmcnt wait doesn't drain the A loads.
    u32x4 pw0;
    {
        const unsigned short* wp = W1T + (long)bn * 384 + 256 + bk;
        pw0 = *(const u32x4*)wp;
    }

    // All GEMM1 A-fragments direct from global; they ARE the ef_old registers
    // kept for the residual.
    short8 efold[4];
    {
        const unsigned short* a0 = ef + (eb + wv * 16 + mn) * HIDDEN + (q << 3);
#pragma unroll
        for (int c = 0; c < 4; ++c) efold[c] = *(const short8*)(a0 + (c << 5));
    }

    f32x4 acc[8];
#pragma unroll
    for (int t = 0; t < 8; ++t) acc[t] = (f32x4)0.0f;

    for (int c = 0; c < 4; ++c) {
        *(u32x4*)&Bs[bn * 40 + bk] = pw0;
        barrier_lgkm();
        if (c + 1 < 4) {
            const unsigned short* wp = W1T + (long)bn * 384 + 256 + ((c + 1) << 5) + bk;
            pw0 = *(const u32x4*)wp;
        }
        short8 af = efold[c];
#pragma unroll
        for (int nt = 0; nt < 8; ++nt) {
            short8 bf = *(short8*)&Bs[(nt * 16 + mn) * 40 + (q << 3)];
            acc[nt] = __builtin_amdgcn_mfma_f32_16x16x32_bf16(af, bf, acc[nt], 0, 0, 0);
        }
        barrier_lgkm();
    }

    // ---- pre -> Hs (C-layout, own 16-row band), packed conversion ----
#pragma unroll
    for (int nt = 0; nt < 8; ++nt)
#pragma unroll
        for (int r = 0; r < 4; r += 2) {
            unsigned int p = pack2(acc[nt][r], acc[nt][r + 1]);
            Hs[(wv * 16 + q * 4 + r)     * 136 + nt * 16 + mn] = (unsigned short)p;
            Hs[(wv * 16 + q * 4 + r + 1) * 136 + nt * 16 + mn] = (unsigned short)(p >> 16);
        }

    // ---- H = relu(pre + Xa[dst] + Xb[src] + b1), row-major, vector gather ----
    // 4 lanes per row, 32 channels each (own band rows only -> no barrier).
    {
        const int row = wv * 16 + (lane >> 2);
        const int ch  = (lane & 3) << 5;
        const unsigned short* xap = Xa + (long)dv[row] * HIDDEN + ch;
        const unsigned short* xbp = Xb + (long)sv[row] * HIDDEN + ch;
        unsigned short* hp = &Hs[row * 136 + ch];
#pragma unroll
        for (int i = 0; i < 4; ++i) {
            u32x4 va = *(const u32x4*)(xap + (i << 3));
            u32x4 vb = *(const u32x4*)(xbp + (i << 3));
            u32x4 vp = *(u32x4*)(hp + (i << 3));
            float fa[8], fb[8], fp[8];
            unpack8u(va, fa); unpack8u(vb, fb); unpack8u(vp, fp);
            const float* bp = b1 + ch + (i << 3);
            u32x4 nw;
            float h0 = fmaxf(fp[0] + fa[0] + fb[0] + bp[0], 0.0f);
            float h1 = fmaxf(fp[1] + fa[1] + fb[1] + bp[1], 0.0f);
            float h2 = fmaxf(fp[2] + fa[2] + fb[2] + bp[2], 0.0f);
            float h3 = fmaxf(fp[3] + fa[3] + fb[3] + bp[3], 0.0f);
            float h4 = fmaxf(fp[4] + fa[4] + fb[4] + bp[4], 0.0f);
            float h5 = fmaxf(fp[5] + fa[5] + fb[5] + bp[5], 0.0f);
            float h6 = fmaxf(fp[6] + fa[6] + fb[6] + bp[6], 0.0f);
            float h7 = fmaxf(fp[7] + fa[7] + fb[7] + bp[7], 0.0f);
            nw.x = pack2(h0, h1); nw.y = pack2(h2, h3);
            nw.z = pack2(h4, h5); nw.w = pack2(h6, h7);
            *(u32x4*)(hp + (i << 3)) = nw;
        }
    }
    // No barrier: GEMM2 A-frags read only this wave's band (DS wave-ordered).

    f32x4 acc2[8];
#pragma unroll
    for (int t = 0; t < 8; ++t) acc2[t] = (f32x4)0.0f;
    {
        const unsigned short* wp = W2T + (long)bn * 128 + bk;
        pw0 = *(const u32x4*)wp;
    }
    for (int c = 0; c < 4; ++c) {
        *(u32x4*)&Bs[bn * 40 + bk] = pw0;
        barrier_lgkm();
        if (c + 1 < 4) {
            const unsigned short* wp = W2T + (long)bn * 128 + ((c + 1) << 5) + bk;
            pw0 = *(const u32x4*)wp;
        }
        short8 af = *(short8*)&Hs[(wv * 16 + mn) * 136 + (c << 5) + (q << 3)];
#pragma unroll
        for (int nt = 0; nt < 8; ++nt) {
            short8 bf = *(short8*)&Bs[(nt * 16 + mn) * 40 + (q << 3)];
            acc2[nt] = __builtin_amdgcn_mfma_f32_16x16x32_bf16(af, bf, acc2[nt], 0, 0, 0);
        }
        barrier_lgkm();
    }

    // ---- m = acc2 + b2 -> Hs (C-layout, own band), packed conversion ----
#pragma unroll
    for (int nt = 0; nt < 8; ++nt) {
        float b2v = b2[nt * 16 + mn];
#pragma unroll
        for (int r = 0; r < 4; r += 2) {
            unsigned int p = pack2(acc2[nt][r] + b2v, acc2[nt][r + 1] + b2v);
            Hs[(wv * 16 + q * 4 + r)     * 136 + nt * 16 + mn] = (unsigned short)p;
            Hs[(wv * 16 + q * 4 + r + 1) * 136 + nt * 16 + mn] = (unsigned short)(p >> 16);
        }
    }

    // ---- ef_new = ef_old(regs) + m : A-frag order, plain store ----
    {
        const int row = wv * 16 + mn;
        unsigned short* ep_ = ef + (eb + row) * HIDDEN + (q << 3);
#pragma unroll
        for (int c = 0; c < 4; ++c) {
            u32x4 mh = *(u32x4*)&Hs[row * 136 + (c << 5) + (q << 3)];
            float m[8], e[8];
            unpack8u(mh, m);
            u32x4 eu = *(u32x4*)&efold[c];
            unpack8u(eu, e);
            u32x4 nw;
            nw.x = pack2(e[0] + m[0], e[1] + m[1]);
            nw.y = pack2(e[2] + m[2], e[3] + m[3]);
            nw.z = pack2(e[4] + m[4], e[5] + m[5]);
            nw.w = pack2(e[6] + m[6], e[7] + m[7]);
            *(u32x4*)(ep_ + (c << 5)) = nw;
        }
    }

    // ---- segmented reduction by dst-run (own 16-row band, barrier-free) ----
    {
        const int cp = lane << 1;
        const int qr = wv;
        float s0 = 0.0f, s1 = 0.0f;
        int cur = dv[qr * 16];
        for (int r = 0; r < 16; ++r) {
            const int row = qr * 16 + r;
            const int d = dv[row];
            if (d != cur) {
                atomicAdd(&sums[(long)cur * HIDDEN + cp], s0);
                atomicAdd(&sums[(long)cur * HIDDEN + cp + 1], s1);
                s0 = 0.0f; s1 = 0.0f;
                cur = d;
            }
            unsigned int u = *(unsigned int*)&Hs[row * 136 + cp];
            s0 += bf2f((unsigned short)(u & 0xffff));
            s1 += bf2f((unsigned short)(u >> 16));
        }
        atomicAdd(&sums[(long)cur * HIDDEN + cp], s0);
        atomicAdd(&sums[(long)cur * HIDDEN + cp + 1], s1);
    }
}

// ---------------------------------------------------------------------------
// MFMA node layer — A-DIRECT variant (round-6, unchanged this round).
// ---------------------------------------------------------------------------
__global__ __launch_bounds__(256, 5)
void node_layer_mfma(float* __restrict__ x,
                     float* __restrict__ sums,
                     const int* __restrict__ deg,
                     const unsigned short* __restrict__ N1T,  // [128][256] bf16
                     const float* __restrict__ b1,
                     const unsigned short* __restrict__ N2T,  // [128][128] bf16
                     const float* __restrict__ b2,
                     const unsigned short* __restrict__ W1Tn, // [128][384] next layer (or null)
                     unsigned short* __restrict__ Xa,
                     unsigned short* __restrict__ Xb)
{
    // 0     .. 17408 : Hs (64 x 136)
    // 17408 .. 27648 : Bs (128 x 40)
    __shared__ __align__(16) unsigned char nbuf[27648];
    unsigned short* Hs = (unsigned short*)nbuf;
    unsigned short* Bs = (unsigned short*)(nbuf + 17408);

    const int tid = threadIdx.x;
    const long n0 = (long)blockIdx.x * 64;

    const int lane = tid & 63;
    const int wv   = tid >> 6;
    const int mn   = lane & 15;
    const int q    = lane >> 4;
    const int srow = tid >> 2;
    const int sseg = tid & 3;
    const int bn   = tid >> 1;
    const int bk   = (tid & 1) << 4;

    // This thread's A-frag row (wave band = rows [wv*16, wv*16+16)).
    long arow = n0 + wv * 16 + mn;
    if (arow >= NNODES) arow = NNODES - 1;
    const float* xr = x + arow * HIDDEN;
    const float* sr = sums + arow * HIDDEN;
    const float cv = 1.0f / fmaxf((float)deg[arow], 1.0f);

    f32x4 acc[8];
#pragma unroll
    for (int t = 0; t < 8; ++t) acc[t] = (f32x4)0.0f;

    float4 pa0, pa1;
    u32x4 pb0, pb1;
    {
        const unsigned short* wp = N1T + (long)bn * 256 + bk;
        pb0 = *(const u32x4*)wp;
        pb1 = *(const u32x4*)(wp + 8);
        const float* ap = xr + (q << 3);
        pa0 = *(const float4*)ap;
        pa1 = *(const float4*)(ap + 4);
    }
    float scCur = 1.0f;
    for (int c = 0; c < 8; ++c) {
        short8 af;
        {
            unsigned int* au = (unsigned int*)&af;
            au[0] = pack2(pa0.x * scCur, pa0.y * scCur);
            au[1] = pack2(pa0.z * scCur, pa0.w * scCur);
            au[2] = pack2(pa1.x * scCur, pa1.y * scCur);
            au[3] = pack2(pa1.z * scCur, pa1.w * scCur);
        }
        *(u32x4*)&Bs[bn * 40 + bk]     = pb0;
        *(u32x4*)&Bs[bn * 40 + bk + 8] = pb1;
        barrier_lgkm();
        if (c + 1 < 8) {
            const int cn = c + 1;
            const float* base = (cn < 4) ? xr : sr;
            scCur = (cn < 4) ? 1.0f : cv;
            const float* ap = base + ((cn & 3) << 5) + (q << 3);
            pa0 = *(const float4*)ap;
            pa1 = *(const float4*)(ap + 4);
            const unsigned short* wp = N1T + (long)bn * 256 + (cn << 5) + bk;
            pb0 = *(const u32x4*)wp;
            pb1 = *(const u32x4*)(wp + 8);
        }
#pragma unroll
        for (int nt = 0; nt < 8; ++nt) {
            short8 bf = *(short8*)&Bs[(nt * 16 + mn) * 40 + (q << 3)];
            acc[nt] = __builtin_amdgcn_mfma_f32_16x16x32_bf16(af, bf, acc[nt], 0, 0, 0);
        }
        barrier_lgkm();
    }

    // zero own sums rows for the next layer
    {
        long row = n0 + srow;
        if (row < NNODES) {
            float4 z = make_float4(0.f, 0.f, 0.f, 0.f);
            float* p = sums + row * HIDDEN + (sseg << 5);
#pragma unroll
            for (int i = 0; i < 8; ++i) ((float4*)p)[i] = z;
        }
    }

#pragma unroll
    for (int nt = 0; nt < 8; ++nt) {
        float b1v = b1[nt * 16 + mn];
#pragma unroll
        for (int r = 0; r < 4; r += 2) {
            float h0 = fmaxf(acc[nt][r]     + b1v, 0.0f);
            float h1 = fmaxf(acc[nt][r + 1] + b1v, 0.0f);
            unsigned int p = pack2(h0, h1);
            Hs[(wv * 16 + q * 4 + r)     * 136 + nt * 16 + mn] = (unsigned short)p;
            Hs[(wv * 16 + q * 4 + r + 1) * 136 + nt * 16 + mn] = (unsigned short)(p >> 16);
        }
    }

    f32x4 acc2[8];
#pragma unroll
    for (int t = 0; t < 8; ++t) acc2[t] = (f32x4)0.0f;
    {
        const unsigned short* wp = N2T + (long)bn * 128 + bk;
        pb0 = *(const u32x4*)wp;
        pb1 = *(const u32x4*)(wp + 8);
    }
    for (int c = 0; c < 4; ++c) {
        *(u32x4*)&Bs[bn * 40 + bk]     = pb0;
        *(u32x4*)&Bs[bn * 40 + bk + 8] = pb1;
        barrier_lgkm();
        if (c + 1 < 4) {
            const unsigned short* wp = N2T + (long)bn * 128 + ((c + 1) << 5) + bk;
            pb0 = *(const u32x4*)wp;
            pb1 = *(const u32x4*)(wp + 8);
        }
        short8 af = *(short8*)&Hs[(wv * 16 + mn) * 136 + (c << 5) + (q << 3)];
#pragma unroll
        for (int nt = 0; nt < 8; ++nt) {
            short8 bf = *(short8*)&Bs[(nt * 16 + mn) * 40 + (q << 3)];
            acc2[nt] = __builtin_amdgcn_mfma_f32_16x16x32_bf16(af, bf, acc2[nt], 0, 0, 0);
        }
        barrier_lgkm();
    }

    // ---- xnew = x + acc2 + b2 (exact fp32); stage xnew bf16 into Hs ----
#pragma unroll
    for (int nt = 0; nt < 8; ++nt) {
        float b2v = b2[nt * 16 + mn];
        float xns[4];
#pragma unroll
        for (int r = 0; r < 4; ++r) {
            long row = n0 + wv * 16 + q * 4 + r;
            float xn = 0.0f;
            if (row < NNODES) {
                float* p = x + row * HIDDEN + nt * 16 + mn;
                xn = *p + acc2[nt][r] + b2v;
                *p = xn;
            }
            xns[r] = xn;
        }
        unsigned int p0 = pack2(xns[0], xns[1]);
        unsigned int p1 = pack2(xns[2], xns[3]);
        Hs[(wv * 16 + q * 4 + 0) * 136 + nt * 16 + mn] = (unsigned short)p0;
        Hs[(wv * 16 + q * 4 + 1) * 136 + nt * 16 + mn] = (unsigned short)(p0 >> 16);
        Hs[(wv * 16 + q * 4 + 2) * 136 + nt * 16 + mn] = (unsigned short)p1;
        Hs[(wv * 16 + q * 4 + 3) * 136 + nt * 16 + mn] = (unsigned short)(p1 >> 16);
    }

    // ---- Xa/Xb for next layer: xnew @ W1a / W1b ----
    if (W1Tn) {
#pragma unroll
        for (int half = 0; half < 2; ++half) {
            f32x4 accN[8];
#pragma unroll
            for (int t = 0; t < 8; ++t) accN[t] = (f32x4)0.0f;
            const int kbase = half << 7;
            {
                const unsigned short* wp = W1Tn + (long)bn * 384 + kbase + bk;
                pb0 = *(const u32x4*)wp;
                pb1 = *(const u32x4*)(wp + 8);
            }
            for (int c = 0; c < 4; ++c) {
                *(u32x4*)&Bs[bn * 40 + bk]     = pb0;
                *(u32x4*)&Bs[bn * 40 + bk + 8] = pb1;
                barrier_lgkm();
                if (c + 1 < 4) {
                    const unsigned short* wp = W1Tn + (long)bn * 384 + kbase + ((c + 1) << 5) + bk;
                    pb0 = *(const u32x4*)wp;
                    pb1 = *(const u32x4*)(wp + 8);
                }
                short8 af = *(short8*)&Hs[(wv * 16 + mn) * 136 + (c << 5) + (q << 3)];
#pragma unroll
                for (int nt = 0; nt < 8; ++nt) {
                    short8 bf = *(short8*)&Bs[(nt * 16 + mn) * 40 + (q << 3)];
                    accN[nt] = __builtin_amdgcn_mfma_f32_16x16x32_bf16(af, bf, accN[nt], 0, 0, 0);
                }
                barrier_lgkm();
            }
            unsigned short* Xout = half ? Xb : Xa;
#pragma unroll
            for (int nt = 0; nt < 8; ++nt) {
#pragma unroll
                for (int r = 0; r < 4; r += 2) {
                    unsigned int p = pack2(accN[nt][r], accN[nt][r + 1]);
                    long row0 = n0 + wv * 16 + q * 4 + r;
                    if (row0 < NNODES)
                        Xout[row0 * HIDDEN + nt * 16 + mn] = (unsigned short)p;
                    if (row0 + 1 < NNODES)
                        Xout[(row0 + 1) * HIDDEN + nt * 16 + mn] = (unsigned short)(p >> 16);
                }
            }
        }
    }
}

// ---------------------------------------------------------------------------
// Decoder + row L2-normalize (one wave per node)
// ---------------------------------------------------------------------------
__global__ void decode_kernel(const float* __restrict__ x,
                              const float* __restrict__ w,
                              const float* __restrict__ b,
                              float* __restrict__ out)
{
    int gid = blockIdx.x * blockDim.x + threadIdx.x;
    int node = gid >> 6;
    int lane = threadIdx.x & 63;
    if (node >= NNODES) return;
    float a0 = 0.f, a1 = 0.f, a2 = 0.f;
#pragma unroll
    for (int k = lane; k < HIDDEN; k += 64) {
        float xv = x[(long)node * HIDDEN + k];
        a0 = fmaf(xv, w[k * 3 + 0], a0);
        a1 = fmaf(xv, w[k * 3 + 1], a1);
        a2 = fmaf(xv, w[k * 3 + 2], a2);
    }
#pragma unroll
    for (int off = 32; off > 0; off >>= 1) {
        a0 += __shfl_down(a0, off);
        a1 += __shfl_down(a1, off);
        a2 += __shfl_down(a2, off);
    }
    if (lane == 0) {
        a0 += b[0]; a1 += b[1]; a2 += b[2];
        float nrm = sqrtf(a0 * a0 + a1 * a1 + a2 * a2);
        float inv = 1.0f / fmaxf(nrm, 1e-12f);
        out[(long)node * 3 + 0] = a0 * inv;
        out[(long)node * 3 + 1] = a1 * inv;
        out[(long)node * 3 + 2] = a2 * inv;
    }
}

// ---------------------------------------------------------------------------
extern "C" void kernel_launch(void* const* d_in, const int* in_sizes, int n_in,
                              void* d_out, int out_size, void* d_ws, size_t ws_size,
                              hipStream_t stream)
{
    const float* edge_attr = (const float*)d_in[1];
    const int*   ei        = (const int*)d_in[2];
    const float* enc_w     = (const float*)d_in[3];
    const float* enc_b     = (const float*)d_in[4];
    const float* dec_w     = (const float*)d_in[5];
    const float* dec_b     = (const float*)d_in[6];
    const float* edge_w1   = (const float*)d_in[7];
    const float* edge_b1   = (const float*)d_in[8];
    const float* edge_w2   = (const float*)d_in[9];
    const float* edge_b2   = (const float*)d_in[10];
    const float* node_w1   = (const float*)d_in[11];
    const float* node_b1   = (const float*)d_in[12];
    const float* node_w2   = (const float*)d_in[13];
    const float* node_b2   = (const float*)d_in[14];

    // workspace layout (bytes), 16B-aligned, total ~255.4 MB
    char* ws = (char*)d_ws;
    unsigned short* ef  = (unsigned short*)(ws);                  // 163,840,000
    float* x      = (float*)(ws + 163840000L);                    //  25,600,000
    float* sums   = (float*)(ws + 189440000L);                    //  25,600,000
    int*   src32  = (int*)  (ws + 215040000L);                    //   2,560,000
    int*   dst32  = (int*)  (ws + 217600000L);                    //   2,560,000
    int*   sp     = (int*)  (ws + 220160000L);                    //   2,560,000
    int*   dp     = (int*)  (ws + 222720000L);                    //   2,560,000
    int*   eperm  = (int*)  (ws + 225280000L);                    //   2,560,000
    int*   deg    = (int*)  (ws + 227840000L);                    //     200,704
    int*   off    = (int*)  (ws + 228040704L);                    //     200,704
    int*   cursor = (int*)  (ws + 228241408L);                    //     200,704
    int*   flag   = (int*)  (ws + 228442112L);                    //          64
    unsigned short* W1T = (unsigned short*)(ws + 228442176L);     //     589,824
    unsigned short* W2T = (unsigned short*)(ws + 229032000L);     //     196,608
    unsigned short* N1T = (unsigned short*)(ws + 229228608L);     //     393,216
    unsigned short* N2T = (unsigned short*)(ws + 229621824L);     //     196,608
    unsigned short* Xa  = (unsigned short*)(ws + 229818432L);     //  12,800,000
    unsigned short* Xb  = (unsigned short*)(ws + 242618432L);     //  12,800,000
    // end: 255,418,432

    float* out = (float*)d_out;

    hipMemsetAsync(x, 0, (size_t)NNODES * HIDDEN * sizeof(float), stream);
    hipMemsetAsync(sums, 0, (size_t)NNODES * HIDDEN * sizeof(float), stream);
    hipMemsetAsync(deg, 0, 200704, stream);
    hipMemsetAsync(Xa, 0, 25600000, stream);   // Xa + Xb (contiguous)

    detect_kernel<<<1, 64, 0, stream>>>(ei, flag);
    normidx_kernel<<<(NEDGES + 255) / 256, 256, 0, stream>>>(ei, flag, src32, dst32);
    degree_kernel<<<(NEDGES + 255) / 256, 256, 0, stream>>>(dst32, deg);
    scan_kernel<<<1, SCAN_T, 0, stream>>>(deg, off, cursor);
    scatter_kernel<<<(NEDGES + 255) / 256, 256, 0, stream>>>(src32, dst32, cursor, sp, dp, eperm);
    encode_kernel<<<(NEDGES * 32 + 255) / 256, 256, 0, stream>>>(edge_attr, enc_w, enc_b, eperm, ef);

    transpose_kernel<<<(6 * 384 * 128 + 255) / 256, 256, 0, stream>>>(edge_w1, W1T, 384, 128, 6);
    transpose_kernel<<<(6 * 128 * 128 + 255) / 256, 256, 0, stream>>>(edge_w2, W2T, 128, 128, 6);
    transpose_kernel<<<(6 * 256 * 128 + 255) / 256, 256, 0, stream>>>(node_w1, N1T, 256, 128, 6);
    transpose_kernel<<<(6 * 128 * 128 + 255) / 256, 256, 0, stream>>>(node_w2, N2T, 128, 128, 6);

    for (int l = 0; l < NLAYERS; ++l) {
        edge_layer_mfma<<<NEDGES / 128, 512, 0, stream>>>(
            Xa, Xb, ef, sums, sp, dp,
            W1T + (long)l * 384 * 128, edge_b1 + (long)l * HIDDEN,
            W2T + (long)l * 128 * 128, edge_b2 + (long)l * HIDDEN);
        const unsigned short* w1next = (l + 1 < NLAYERS) ? (W1T + (long)(l + 1) * 384 * 128) : nullptr;
        node_layer_mfma<<<(NNODES + 63) / 64, 256, 0, stream>>>(
            x, sums, deg,
            N1T + (long)l * 256 * 128, node_b1 + (long)l * HIDDEN,
            N2T + (long)l * 128 * 128, node_b2 + (long)l * HIDDEN,
            w1next, Xa, Xb);
    }

    decode_kernel<<<(NNODES * 64 + 255) / 256, 256, 0, stream>>>(x, dec_w, dec_b, out);
}

// Round 8
// 1498.611 us; speedup vs baseline: 1.0845x; 1.0845x over previous
//
#include <hip/hip_runtime.h>
#include <cstdint>

#define HIDDEN  128
#define NLAYERS 6
#define NNODES  50000
#define NEDGES  640000

typedef short short8 __attribute__((ext_vector_type(8)));
typedef float f32x4  __attribute__((ext_vector_type(4)));
typedef unsigned int   u32x4 __attribute__((ext_vector_type(4)));
typedef unsigned int   u32x2 __attribute__((ext_vector_type(2)));

// ---- bf16 <-> f32 helpers -------------------------------------------------
__device__ __forceinline__ float bf2f(unsigned short u) {
    return __uint_as_float(((unsigned int)u) << 16);
}
__device__ __forceinline__ unsigned short f2bf(float f) {
    unsigned int u = __float_as_uint(f);
    unsigned int r = u + 0x7FFFu + ((u >> 16) & 1u);
    return (unsigned short)(r >> 16);
}
// HW packed conversion: v_cvt_pk_bf16_f32 (RNE) == f2bf(a) | f2bf(b)<<16.
__device__ __forceinline__ unsigned int pack2(float a, float b) {
    unsigned int r;
    asm("v_cvt_pk_bf16_f32 %0, %1, %2" : "=v"(r) : "v"(a), "v"(b));
    return r;
}
__device__ __forceinline__ void unpack8u(u32x4 v, float* f) {
    f[0] = bf2f((unsigned short)(v.x & 0xffff)); f[1] = bf2f((unsigned short)(v.x >> 16));
    f[2] = bf2f((unsigned short)(v.y & 0xffff)); f[3] = bf2f((unsigned short)(v.y >> 16));
    f[4] = bf2f((unsigned short)(v.z & 0xffff)); f[5] = bf2f((unsigned short)(v.z >> 16));
    f[6] = bf2f((unsigned short)(v.w & 0xffff)); f[7] = bf2f((unsigned short)(v.w >> 16));
}

// ---- barrier that drains ONLY lgkmcnt (LDS); prefetched global loads stay
//      in flight across it. Cross-wave deps here flow through LDS only.
__device__ __forceinline__ void barrier_lgkm() {
    asm volatile("s_waitcnt lgkmcnt(0)" ::: "memory");
    __builtin_amdgcn_s_barrier();
    __builtin_amdgcn_sched_barrier(0);
}

// ---------------------------------------------------------------------------
// Index dtype detection + canonicalization
// ---------------------------------------------------------------------------
__global__ void detect_kernel(const int* __restrict__ ei, int* __restrict__ flag)
{
    int lane = threadIdx.x;
    int v = ei[2 * lane + 1];
    unsigned long long b = __ballot(v != 0);
    if (lane == 0) *flag = (b != 0ULL) ? 1 : 0;
}

__global__ void normidx_kernel(const int* __restrict__ ei, const int* __restrict__ flag,
                               int* __restrict__ s32, int* __restrict__ d32)
{
    int e = blockIdx.x * blockDim.x + threadIdx.x;
    if (e >= NEDGES) return;
    int s, d;
    if (*flag) { s = ei[e]; d = ei[NEDGES + e]; }
    else       { s = ei[2 * e]; d = ei[2 * (NEDGES + e)]; }
    s32[e] = min(max(s, 0), NNODES - 1);
    d32[e] = min(max(d, 0), NNODES - 1);
}

__global__ void degree_kernel(const int* __restrict__ dst, int* __restrict__ deg)
{
    int e = blockIdx.x * blockDim.x + threadIdx.x;
    if (e < NEDGES) atomicAdd(&deg[dst[e]], 1);
}

// ---------------------------------------------------------------------------
// Exclusive scan over deg[0..NNODES) -> off, cursor. One 1024-thread block.
// ---------------------------------------------------------------------------
#define SCAN_T 1024
__global__ void scan_kernel(const int* __restrict__ deg, int* __restrict__ off,
                            int* __restrict__ cursor)
{
    __shared__ int part[SCAN_T];
    const int t = threadIdx.x;
    const int CH = (NNODES + SCAN_T - 1) / SCAN_T;
    const int base = t * CH;
    int s = 0;
    for (int i = 0; i < CH; ++i) {
        int idx = base + i;
        if (idx < NNODES) s += deg[idx];
    }
    part[t] = s;
    __syncthreads();
    for (int d = 1; d < SCAN_T; d <<= 1) {
        int v = (t >= d) ? part[t - d] : 0;
        __syncthreads();
        part[t] += v;
        __syncthreads();
    }
    int run = (t == 0) ? 0 : part[t - 1];
    for (int i = 0; i < CH; ++i) {
        int idx = base + i;
        if (idx < NNODES) {
            off[idx] = run;
            cursor[idx] = run;
            run += deg[idx];
        }
    }
    if (t == SCAN_T - 1) off[NNODES] = run;
}

__global__ void scatter_kernel(const int* __restrict__ s32, const int* __restrict__ d32,
                               int* __restrict__ cursor,
                               int* __restrict__ sp, int* __restrict__ dp, int* __restrict__ ep)
{
    int e = blockIdx.x * blockDim.x + threadIdx.x;
    if (e >= NEDGES) return;
    int d = d32[e];
    int p = atomicAdd(&cursor[d], 1);
    sp[p] = s32[e];
    dp[p] = d;
    ep[p] = e;
}

// ---------------------------------------------------------------------------
// Weight transpose+convert: W [L][K][N] fp32 -> WT [L][N][K] bf16
// ---------------------------------------------------------------------------
__global__ void transpose_kernel(const float* __restrict__ W, unsigned short* __restrict__ WT,
                                 int K, int N, int L)
{
    long idx = (long)blockIdx.x * 256 + threadIdx.x;
    long tot = (long)L * K * N;
    if (idx >= tot) return;
    int kn = (int)(idx % ((long)K * N));
    int l  = (int)(idx / ((long)K * N));
    int k = kn / N;
    int n = kn % N;
    WT[(long)l * K * N + (long)n * K + k] = f2bf(W[idx]);
}

// ---------------------------------------------------------------------------
// Encoder into permuted layout: ef[p] = enc(ea[ep[p]])
// ---------------------------------------------------------------------------
__global__ void encode_kernel(const float* __restrict__ ea,
                              const float* __restrict__ w,
                              const float* __restrict__ b,
                              const int* __restrict__ ep,
                              unsigned short* __restrict__ ef)
{
    int idx = blockIdx.x * blockDim.x + threadIdx.x;
    int p = idx >> 5;
    if (p >= NEDGES) return;
    int e = ep[p];
    int j = (idx & 31) << 2;
    float a0 = ea[e * 3 + 0], a1 = ea[e * 3 + 1], a2 = ea[e * 3 + 2];
    float4 w0 = *(const float4*)(w + 0 * HIDDEN + j);
    float4 w1 = *(const float4*)(w + 1 * HIDDEN + j);
    float4 w2 = *(const float4*)(w + 2 * HIDDEN + j);
    float4 bb = *(const float4*)(b + j);
    ushort4 o;
    o.x = f2bf(fmaf(a0, w0.x, fmaf(a1, w1.x, fmaf(a2, w2.x, bb.x))));
    o.y = f2bf(fmaf(a0, w0.y, fmaf(a1, w1.y, fmaf(a2, w2.y, bb.y))));
    o.z = f2bf(fmaf(a0, w0.z, fmaf(a1, w1.z, fmaf(a2, w2.z, bb.z))));
    o.w = f2bf(fmaf(a0, w0.w, fmaf(a1, w1.w, fmaf(a2, w2.w, bb.w))));
    *(ushort4*)(ef + (long)p * HIDDEN + j) = o;
}

// ---------------------------------------------------------------------------
// MFMA edge layer — round-6 A-DIRECT variant, 4 waves (best measured: 161 µs).
// Round-7 showed 8-wave regresses (atomic flush churn); reverted.
// ---------------------------------------------------------------------------
__global__ __launch_bounds__(256, 3)
void edge_layer_mfma(const unsigned short* __restrict__ Xa,   // [N][128] bf16
                     const unsigned short* __restrict__ Xb,   // [N][128] bf16
                     unsigned short* __restrict__ ef,
                     float* __restrict__ sums,
                     const int* __restrict__ sp,
                     const int* __restrict__ dp,
                     const unsigned short* __restrict__ W1T,  // [128][384] bf16; W1c at k+256
                     const float* __restrict__ b1,
                     const unsigned short* __restrict__ W2T,  // [128][128] bf16
                     const float* __restrict__ b2)
{
    __shared__ __align__(16) unsigned char buf[45056];
    unsigned short* Hs = (unsigned short*)buf;               // 128 x 136
    unsigned short* Bs = (unsigned short*)(buf + 34816);     // 128 x 40
    __shared__ int dv[128];
    __shared__ int sv[128];

    const int tid = threadIdx.x;
    // XCD-chunked swizzle: grid = 5000 (= 8 x 625). Each XCD gets a contiguous
    // edge (= dst) range -> sums atomic lines stay in its private L2.
    const int nwg = (int)gridDim.x;
    const int bid = (int)blockIdx.x;
    const int sb  = (bid & 7) * (nwg >> 3) + (bid >> 3);
    const long eb = (long)sb * 128;

    if (tid < 128) dv[tid]       = dp[eb + tid];
    else           sv[tid - 128] = sp[eb + tid - 128];

    const int lane = tid & 63;
    const int wv   = tid >> 6;
    const int mn   = lane & 15;
    const int q    = lane >> 4;
    const int bn   = tid >> 1;
    const int bk   = (tid & 1) << 4;

    // W chunk-0 prefetch FIRST so its vmcnt wait doesn't drain the A loads.
    u32x4 pw0, pw1;
    {
        const unsigned short* wp = W1T + (long)bn * 384 + 256 + bk;
        pw0 = *(const u32x4*)wp;
        pw1 = *(const u32x4*)(wp + 8);
    }

    // All GEMM1 A-fragments direct from global; they ARE the ef_old registers
    // kept for the residual. 16 x 16B loads in flight.
    short8 efold0[4], efold1[4];
    {
        const unsigned short* a0 = ef + (eb + wv * 32 + mn) * HIDDEN + (q << 3);
        const unsigned short* a1 = a0 + 16 * HIDDEN;
#pragma unroll
        for (int c = 0; c < 4; ++c) {
            efold0[c] = *(const short8*)(a0 + (c << 5));
            efold1[c] = *(const short8*)(a1 + (c << 5));
        }
    }

    f32x4 acc[2][8];
#pragma unroll
    for (int h = 0; h < 2; ++h)
#pragma unroll
        for (int t = 0; t < 8; ++t) acc[h][t] = (f32x4)0.0f;

    for (int c = 0; c < 4; ++c) {
        *(u32x4*)&Bs[bn * 40 + bk]     = pw0;
        *(u32x4*)&Bs[bn * 40 + bk + 8] = pw1;
        barrier_lgkm();
        if (c + 1 < 4) {
            const unsigned short* wp = W1T + (long)bn * 384 + 256 + ((c + 1) << 5) + bk;
            pw0 = *(const u32x4*)wp;
            pw1 = *(const u32x4*)(wp + 8);
        }
        short8 af0 = efold0[c];
        short8 af1 = efold1[c];
#pragma unroll
        for (int nt = 0; nt < 8; ++nt) {
            short8 bf = *(short8*)&Bs[(nt * 16 + mn) * 40 + (q << 3)];
            acc[0][nt] = __builtin_amdgcn_mfma_f32_16x16x32_bf16(af0, bf, acc[0][nt], 0, 0, 0);
            acc[1][nt] = __builtin_amdgcn_mfma_f32_16x16x32_bf16(af1, bf, acc[1][nt], 0, 0, 0);
        }
        barrier_lgkm();
    }

    // ---- pre -> Hs (C-layout, own wave band), packed conversion ----
#pragma unroll
    for (int h = 0; h < 2; ++h)
#pragma unroll
        for (int nt = 0; nt < 8; ++nt)
#pragma unroll
            for (int r = 0; r < 4; r += 2) {
                unsigned int p = pack2(acc[h][nt][r], acc[h][nt][r + 1]);
                Hs[(wv * 32 + h * 16 + q * 4 + r)     * 136 + nt * 16 + mn] = (unsigned short)p;
                Hs[(wv * 32 + h * 16 + q * 4 + r + 1) * 136 + nt * 16 + mn] = (unsigned short)(p >> 16);
            }

    // ---- H = relu(pre + Xa[dst] + Xb[src] + b1), row-major, vector gather ----
    {
        const int row  = wv * 32 + (lane >> 1);
        const int ch   = (lane & 1) << 6;
        const unsigned short* xap = Xa + (long)dv[row] * HIDDEN + ch;
        const unsigned short* xbp = Xb + (long)sv[row] * HIDDEN + ch;
        unsigned short* hp = &Hs[row * 136 + ch];
#pragma unroll
        for (int i = 0; i < 8; ++i) {
            u32x4 va = *(const u32x4*)(xap + (i << 3));
            u32x4 vb = *(const u32x4*)(xbp + (i << 3));
            u32x4 vp = *(u32x4*)(hp + (i << 3));
            float fa[8], fb[8], fp[8];
            unpack8u(va, fa); unpack8u(vb, fb); unpack8u(vp, fp);
            const float* bp = b1 + ch + (i << 3);
            u32x4 nw;
            float h0 = fmaxf(fp[0] + fa[0] + fb[0] + bp[0], 0.0f);
            float h1 = fmaxf(fp[1] + fa[1] + fb[1] + bp[1], 0.0f);
            float h2 = fmaxf(fp[2] + fa[2] + fb[2] + bp[2], 0.0f);
            float h3 = fmaxf(fp[3] + fa[3] + fb[3] + bp[3], 0.0f);
            float h4 = fmaxf(fp[4] + fa[4] + fb[4] + bp[4], 0.0f);
            float h5 = fmaxf(fp[5] + fa[5] + fb[5] + bp[5], 0.0f);
            float h6 = fmaxf(fp[6] + fa[6] + fb[6] + bp[6], 0.0f);
            float h7 = fmaxf(fp[7] + fa[7] + fb[7] + bp[7], 0.0f);
            nw.x = pack2(h0, h1); nw.y = pack2(h2, h3);
            nw.z = pack2(h4, h5); nw.w = pack2(h6, h7);
            *(u32x4*)(hp + (i << 3)) = nw;
        }
    }
    // No barrier: GEMM2 A-frags read only this wave's band (DS wave-ordered).

    f32x4 acc2[2][8];
#pragma unroll
    for (int h = 0; h < 2; ++h)
#pragma unroll
        for (int t = 0; t < 8; ++t) acc2[h][t] = (f32x4)0.0f;
    {
        const unsigned short* wp = W2T + (long)bn * 128 + bk;
        pw0 = *(const u32x4*)wp;
        pw1 = *(const u32x4*)(wp + 8);
    }
    for (int c = 0; c < 4; ++c) {
        *(u32x4*)&Bs[bn * 40 + bk]     = pw0;
        *(u32x4*)&Bs[bn * 40 + bk + 8] = pw1;
        barrier_lgkm();
        if (c + 1 < 4) {
            const unsigned short* wp = W2T + (long)bn * 128 + ((c + 1) << 5) + bk;
            pw0 = *(const u32x4*)wp;
            pw1 = *(const u32x4*)(wp + 8);
        }
        short8 af0 = *(short8*)&Hs[(wv * 32 + mn) * 136 + (c << 5) + (q << 3)];
        short8 af1 = *(short8*)&Hs[(wv * 32 + 16 + mn) * 136 + (c << 5) + (q << 3)];
#pragma unroll
        for (int nt = 0; nt < 8; ++nt) {
            short8 bf = *(short8*)&Bs[(nt * 16 + mn) * 40 + (q << 3)];
            acc2[0][nt] = __builtin_amdgcn_mfma_f32_16x16x32_bf16(af0, bf, acc2[0][nt], 0, 0, 0);
            acc2[1][nt] = __builtin_amdgcn_mfma_f32_16x16x32_bf16(af1, bf, acc2[1][nt], 0, 0, 0);
        }
        barrier_lgkm();
    }

    // ---- m = acc2 + b2 -> Hs (C-layout, own band), packed conversion ----
#pragma unroll
    for (int h = 0; h < 2; ++h)
#pragma unroll
        for (int nt = 0; nt < 8; ++nt) {
            float b2v = b2[nt * 16 + mn];
#pragma unroll
            for (int r = 0; r < 4; r += 2) {
                unsigned int p = pack2(acc2[h][nt][r] + b2v, acc2[h][nt][r + 1] + b2v);
                Hs[(wv * 32 + h * 16 + q * 4 + r)     * 136 + nt * 16 + mn] = (unsigned short)p;
                Hs[(wv * 32 + h * 16 + q * 4 + r + 1) * 136 + nt * 16 + mn] = (unsigned short)(p >> 16);
            }
        }

    // ---- ef_new = ef_old(regs) + m : A-frag order, plain store ----
#pragma unroll
    for (int h = 0; h < 2; ++h) {
        const int row = wv * 32 + h * 16 + mn;
        unsigned short* ep_ = ef + (eb + row) * HIDDEN + (q << 3);
#pragma unroll
        for (int c = 0; c < 4; ++c) {
            u32x4 mh = *(u32x4*)&Hs[row * 136 + (c << 5) + (q << 3)];
            float m[8], e[8];
            unpack8u(mh, m);
            short8 eo = h ? efold1[c] : efold0[c];
            u32x4 eu = *(u32x4*)&eo;
            unpack8u(eu, e);
            u32x4 nw;
            nw.x = pack2(e[0] + m[0], e[1] + m[1]);
            nw.y = pack2(e[2] + m[2], e[3] + m[3]);
            nw.z = pack2(e[4] + m[4], e[5] + m[5]);
            nw.w = pack2(e[6] + m[6], e[7] + m[7]);
            *(u32x4*)(ep_ + (c << 5)) = nw;
        }
    }

    // ---- segmented reduction by dst-run (own band rows, barrier-free) ----
    {
        const int cp = (tid & 63) << 1;
        const int qr = tid >> 6;
        float s0 = 0.0f, s1 = 0.0f;
        int cur = dv[qr * 32];
        for (int r = 0; r < 32; ++r) {
            const int row = qr * 32 + r;
            const int d = dv[row];
            if (d != cur) {
                atomicAdd(&sums[(long)cur * HIDDEN + cp], s0);
                atomicAdd(&sums[(long)cur * HIDDEN + cp + 1], s1);
                s0 = 0.0f; s1 = 0.0f;
                cur = d;
            }
            unsigned int u = *(unsigned int*)&Hs[row * 136 + cp];
            s0 += bf2f((unsigned short)(u & 0xffff));
            s1 += bf2f((unsigned short)(u >> 16));
        }
        atomicAdd(&sums[(long)cur * HIDDEN + cp], s0);
        atomicAdd(&sums[(long)cur * HIDDEN + cp + 1], s1);
    }
}

// ---------------------------------------------------------------------------
// MFMA node layer — 8-WAVE OUTPUT-SPLIT variant: 512 threads, same 64-node
// tile, same 27.9 KB LDS. Wave = (row-band wb = wv&3, nt-half nh = wv>>2);
// per-wave acc arrays halve to [4]. Same grid (782) -> ~24 waves/CU (was 12).
// Cross-wave H-row deps (GEMM2+ A-frags span both nt-halves) are synced by
// the existing Bs-stage barrier_lgkm. Per-output MFMA chains identical.
// ---------------------------------------------------------------------------
__global__ __launch_bounds__(512, 6)
void node_layer_mfma(float* __restrict__ x,
                     float* __restrict__ sums,
                     const int* __restrict__ deg,
                     const unsigned short* __restrict__ N1T,  // [128][256] bf16
                     const float* __restrict__ b1,
                     const unsigned short* __restrict__ N2T,  // [128][128] bf16
                     const float* __restrict__ b2,
                     const unsigned short* __restrict__ W1Tn, // [128][384] next layer (or null)
                     unsigned short* __restrict__ Xa,
                     unsigned short* __restrict__ Xb)
{
    // 0     .. 17408 : Hs (64 x 136) / As (64 x 40) aliased
    // 17408 .. 27648 : Bs (128 x 40)
    __shared__ __align__(16) unsigned char nbuf[27648];
    unsigned short* As = (unsigned short*)nbuf;
    unsigned short* Hs = (unsigned short*)nbuf;
    unsigned short* Bs = (unsigned short*)(nbuf + 17408);
    __shared__ float cInv[64];

    const int tid = threadIdx.x;
    const long n0 = (long)blockIdx.x * 64;
    if (tid < 64) {
        long n = n0 + tid;
        cInv[tid] = (n < NNODES) ? 1.0f / fmaxf((float)deg[n], 1.0f) : 0.0f;
    }

    const int lane = tid & 63;
    const int wv   = tid >> 6;        // 0..7
    const int wb   = wv & 3;          // row band: rows [wb*16, wb*16+16)
    const int nh   = wv >> 2;         // nt half: output cols [nh*64, nh*64+64)
    const int mn   = lane & 15;
    const int q    = lane >> 4;
    const int srow = tid >> 3;        // 0..63  (A-staging / zeroing row)
    const int ss   = tid & 7;         // staging seg: 4 floats
    const int bn   = tid >> 2;        // 0..127 (B-staging row)
    const int bk   = (tid & 3) << 3;  // B-staging col offset (shorts)

    long nr = n0 + srow;
    if (nr >= NNODES) nr = NNODES - 1;

    barrier_lgkm();   // cInv visible to all waves

    f32x4 acc[4];
#pragma unroll
    for (int t = 0; t < 4; ++t) acc[t] = (f32x4)0.0f;

    float4 pa;
    u32x4 pb;
    {
        const float* spx = x + nr * HIDDEN + (ss << 2);
        pa = *(const float4*)spx;
        const unsigned short* wp = N1T + (long)bn * 256 + bk;
        pb = *(const u32x4*)wp;
    }
    float scCur = 1.0f;
    for (int c = 0; c < 8; ++c) {
        {
            u32x2 w;
            w.x = pack2(pa.x * scCur, pa.y * scCur);
            w.y = pack2(pa.z * scCur, pa.w * scCur);
            *(u32x2*)&As[srow * 40 + (ss << 2)] = w;
        }
        *(u32x4*)&Bs[bn * 40 + bk] = pb;
        barrier_lgkm();
        if (c + 1 < 8) {
            const int cn = c + 1;
            const float* base = (cn < 4) ? x : sums;
            scCur = (cn < 4) ? 1.0f : cInv[srow];
            const float* spx = base + nr * HIDDEN + ((cn & 3) << 5) + (ss << 2);
            pa = *(const float4*)spx;
            const unsigned short* wp = N1T + (long)bn * 256 + (cn << 5) + bk;
            pb = *(const u32x4*)wp;
        }
        short8 af = *(short8*)&As[(wb * 16 + mn) * 40 + (q << 3)];
#pragma unroll
        for (int nt = 0; nt < 4; ++nt) {
            const int ntp = nh * 4 + nt;
            short8 bf = *(short8*)&Bs[(ntp * 16 + mn) * 40 + (q << 3)];
            acc[nt] = __builtin_amdgcn_mfma_f32_16x16x32_bf16(af, bf, acc[nt], 0, 0, 0);
        }
        barrier_lgkm();
    }
    // As reads done (final barrier above) -> Hs alias safe.

    // zero own sums rows for the next layer. Row srow is loaded AND zeroed by
    // the same wave (8 consecutive tids per row) -> wave-lockstep safe.
    {
        long row = n0 + srow;
        if (row < NNODES) {
            float4 z = make_float4(0.f, 0.f, 0.f, 0.f);
            float* p = sums + row * HIDDEN + (ss << 4);
#pragma unroll
            for (int i = 0; i < 4; ++i) ((float4*)p)[i] = z;
        }
    }

    // ---- H = relu(acc + b1) -> Hs (own rowband x nt-half quadrant) ----
#pragma unroll
    for (int nt = 0; nt < 4; ++nt) {
        const int ntp = nh * 4 + nt;
        float b1v = b1[ntp * 16 + mn];
#pragma unroll
        for (int r = 0; r < 4; r += 2) {
            float h0 = fmaxf(acc[nt][r]     + b1v, 0.0f);
            float h1 = fmaxf(acc[nt][r + 1] + b1v, 0.0f);
            unsigned int p = pack2(h0, h1);
            Hs[(wb * 16 + q * 4 + r)     * 136 + ntp * 16 + mn] = (unsigned short)p;
            Hs[(wb * 16 + q * 4 + r + 1) * 136 + ntp * 16 + mn] = (unsigned short)(p >> 16);
        }
    }

    f32x4 acc2[4];
#pragma unroll
    for (int t = 0; t < 4; ++t) acc2[t] = (f32x4)0.0f;
    {
        const unsigned short* wp = N2T + (long)bn * 128 + bk;
        pb = *(const u32x4*)wp;
    }
    for (int c = 0; c < 4; ++c) {
        *(u32x4*)&Bs[bn * 40 + bk] = pb;
        barrier_lgkm();   // also syncs partner wave's H quadrant writes
        if (c + 1 < 4) {
            const unsigned short* wp = N2T + (long)bn * 128 + ((c + 1) << 5) + bk;
            pb = *(const u32x4*)wp;
        }
        short8 af = *(short8*)&Hs[(wb * 16 + mn) * 136 + (c << 5) + (q << 3)];
#pragma unroll
        for (int nt = 0; nt < 4; ++nt) {
            const int ntp = nh * 4 + nt;
            short8 bf = *(short8*)&Bs[(ntp * 16 + mn) * 40 + (q << 3)];
            acc2[nt] = __builtin_amdgcn_mfma_f32_16x16x32_bf16(af, bf, acc2[nt], 0, 0, 0);
        }
        barrier_lgkm();
    }

    // ---- xnew = x + acc2 + b2 (exact fp32); stage xnew bf16 into Hs ----
#pragma unroll
    for (int nt = 0; nt < 4; ++nt) {
        const int ntp = nh * 4 + nt;
        float b2v = b2[ntp * 16 + mn];
        float xns[4];
#pragma unroll
        for (int r = 0; r < 4; ++r) {
            long row = n0 + wb * 16 + q * 4 + r;
            float xn = 0.0f;
            if (row < NNODES) {
                float* p = x + row * HIDDEN + ntp * 16 + mn;
                xn = *p + acc2[nt][r] + b2v;
                *p = xn;
            }
            xns[r] = xn;
        }
        unsigned int p0 = pack2(xns[0], xns[1]);
        unsigned int p1 = pack2(xns[2], xns[3]);
        Hs[(wb * 16 + q * 4 + 0) * 136 + ntp * 16 + mn] = (unsigned short)p0;
        Hs[(wb * 16 + q * 4 + 1) * 136 + ntp * 16 + mn] = (unsigned short)(p0 >> 16);
        Hs[(wb * 16 + q * 4 + 2) * 136 + ntp * 16 + mn] = (unsigned short)p1;
        Hs[(wb * 16 + q * 4 + 3) * 136 + ntp * 16 + mn] = (unsigned short)(p1 >> 16);
    }

    // ---- Xa/Xb for next layer: xnew @ W1a / W1b ----
    if (W1Tn) {
#pragma unroll
        for (int half = 0; half < 2; ++half) {
            f32x4 accN[4];
#pragma unroll
            for (int t = 0; t < 4; ++t) accN[t] = (f32x4)0.0f;
            const int kbase = half << 7;
            {
                const unsigned short* wp = W1Tn + (long)bn * 384 + kbase + bk;
                pb = *(const u32x4*)wp;
            }
            for (int c = 0; c < 4; ++c) {
                *(u32x4*)&Bs[bn * 40 + bk] = pb;
                barrier_lgkm();   // also syncs partner wave's xnew Hs writes
                if (c + 1 < 4) {
                    const unsigned short* wp = W1Tn + (long)bn * 384 + kbase + ((c + 1) << 5) + bk;
                    pb = *(const u32x4*)wp;
                }
                short8 af = *(short8*)&Hs[(wb * 16 + mn) * 136 + (c << 5) + (q << 3)];
#pragma unroll
                for (int nt = 0; nt < 4; ++nt) {
                    const int ntp = nh * 4 + nt;
                    short8 bf = *(short8*)&Bs[(ntp * 16 + mn) * 40 + (q << 3)];
                    accN[nt] = __builtin_amdgcn_mfma_f32_16x16x32_bf16(af, bf, accN[nt], 0, 0, 0);
                }
                barrier_lgkm();
            }
            unsigned short* Xout = half ? Xb : Xa;
#pragma unroll
            for (int nt = 0; nt < 4; ++nt) {
                const int ntp = nh * 4 + nt;
#pragma unroll
                for (int r = 0; r < 4; r += 2) {
                    unsigned int p = pack2(accN[nt][r], accN[nt][r + 1]);
                    long row0 = n0 + wb * 16 + q * 4 + r;
                    if (row0 < NNODES)
                        Xout[row0 * HIDDEN + ntp * 16 + mn] = (unsigned short)p;
                    if (row0 + 1 < NNODES)
                        Xout[(row0 + 1) * HIDDEN + ntp * 16 + mn] = (unsigned short)(p >> 16);
                }
            }
        }
    }
}

// ---------------------------------------------------------------------------
// Decoder + row L2-normalize (one wave per node)
// ---------------------------------------------------------------------------
__global__ void decode_kernel(const float* __restrict__ x,
                              const float* __restrict__ w,
                              const float* __restrict__ b,
                              float* __restrict__ out)
{
    int gid = blockIdx.x * blockDim.x + threadIdx.x;
    int node = gid >> 6;
    int lane = threadIdx.x & 63;
    if (node >= NNODES) return;
    float a0 = 0.f, a1 = 0.f, a2 = 0.f;
#pragma unroll
    for (int k = lane; k < HIDDEN; k += 64) {
        float xv = x[(long)node * HIDDEN + k];
        a0 = fmaf(xv, w[k * 3 + 0], a0);
        a1 = fmaf(xv, w[k * 3 + 1], a1);
        a2 = fmaf(xv, w[k * 3 + 2], a2);
    }
#pragma unroll
    for (int off = 32; off > 0; off >>= 1) {
        a0 += __shfl_down(a0, off);
        a1 += __shfl_down(a1, off);
        a2 += __shfl_down(a2, off);
    }
    if (lane == 0) {
        a0 += b[0]; a1 += b[1]; a2 += b[2];
        float nrm = sqrtf(a0 * a0 + a1 * a1 + a2 * a2);
        float inv = 1.0f / fmaxf(nrm, 1e-12f);
        out[(long)node * 3 + 0] = a0 * inv;
        out[(long)node * 3 + 1] = a1 * inv;
        out[(long)node * 3 + 2] = a2 * inv;
    }
}

// ---------------------------------------------------------------------------
extern "C" void kernel_launch(void* const* d_in, const int* in_sizes, int n_in,
                              void* d_out, int out_size, void* d_ws, size_t ws_size,
                              hipStream_t stream)
{
    const float* edge_attr = (const float*)d_in[1];
    const int*   ei        = (const int*)d_in[2];
    const float* enc_w     = (const float*)d_in[3];
    const float* enc_b     = (const float*)d_in[4];
    const float* dec_w     = (const float*)d_in[5];
    const float* dec_b     = (const float*)d_in[6];
    const float* edge_w1   = (const float*)d_in[7];
    const float* edge_b1   = (const float*)d_in[8];
    const float* edge_w2   = (const float*)d_in[9];
    const float* edge_b2   = (const float*)d_in[10];
    const float* node_w1   = (const float*)d_in[11];
    const float* node_b1   = (const float*)d_in[12];
    const float* node_w2   = (const float*)d_in[13];
    const float* node_b2   = (const float*)d_in[14];

    // workspace layout (bytes), 16B-aligned, total ~255.4 MB
    char* ws = (char*)d_ws;
    unsigned short* ef  = (unsigned short*)(ws);                  // 163,840,000
    float* x      = (float*)(ws + 163840000L);                    //  25,600,000
    float* sums   = (float*)(ws + 189440000L);                    //  25,600,000
    int*   src32  = (int*)  (ws + 215040000L);                    //   2,560,000
    int*   dst32  = (int*)  (ws + 217600000L);                    //   2,560,000
    int*   sp     = (int*)  (ws + 220160000L);                    //   2,560,000
    int*   dp     = (int*)  (ws + 222720000L);                    //   2,560,000
    int*   eperm  = (int*)  (ws + 225280000L);                    //   2,560,000
    int*   deg    = (int*)  (ws + 227840000L);                    //     200,704
    int*   off    = (int*)  (ws + 228040704L);                    //     200,704
    int*   cursor = (int*)  (ws + 228241408L);                    //     200,704
    int*   flag   = (int*)  (ws + 228442112L);                    //          64
    unsigned short* W1T = (unsigned short*)(ws + 228442176L);     //     589,824
    unsigned short* W2T = (unsigned short*)(ws + 229032000L);     //     196,608
    unsigned short* N1T = (unsigned short*)(ws + 229228608L);     //     393,216
    unsigned short* N2T = (unsigned short*)(ws + 229621824L);     //     196,608
    unsigned short* Xa  = (unsigned short*)(ws + 229818432L);     //  12,800,000
    unsigned short* Xb  = (unsigned short*)(ws + 242618432L);     //  12,800,000
    // end: 255,418,432

    float* out = (float*)d_out;

    hipMemsetAsync(x, 0, (size_t)NNODES * HIDDEN * sizeof(float), stream);
    hipMemsetAsync(sums, 0, (size_t)NNODES * HIDDEN * sizeof(float), stream);
    hipMemsetAsync(deg, 0, 200704, stream);
    hipMemsetAsync(Xa, 0, 25600000, stream);   // Xa + Xb (contiguous)

    detect_kernel<<<1, 64, 0, stream>>>(ei, flag);
    normidx_kernel<<<(NEDGES + 255) / 256, 256, 0, stream>>>(ei, flag, src32, dst32);
    degree_kernel<<<(NEDGES + 255) / 256, 256, 0, stream>>>(dst32, deg);
    scan_kernel<<<1, SCAN_T, 0, stream>>>(deg, off, cursor);
    scatter_kernel<<<(NEDGES + 255) / 256, 256, 0, stream>>>(src32, dst32, cursor, sp, dp, eperm);
    encode_kernel<<<(NEDGES * 32 + 255) / 256, 256, 0, stream>>>(edge_attr, enc_w, enc_b, eperm, ef);

    transpose_kernel<<<(6 * 384 * 128 + 255) / 256, 256, 0, stream>>>(edge_w1, W1T, 384, 128, 6);
    transpose_kernel<<<(6 * 128 * 128 + 255) / 256, 256, 0, stream>>>(edge_w2, W2T, 128, 128, 6);
    transpose_kernel<<<(6 * 256 * 128 + 255) / 256, 256, 0, stream>>>(node_w1, N1T, 256, 128, 6);
    transpose_kernel<<<(6 * 128 * 128 + 255) / 256, 256, 0, stream>>>(node_w2, N2T, 128, 128, 6);

    for (int l = 0; l < NLAYERS; ++l) {
        edge_layer_mfma<<<NEDGES / 128, 256, 0, stream>>>(
            Xa, Xb, ef, sums, sp, dp,
            W1T + (long)l * 384 * 128, edge_b1 + (long)l * HIDDEN,
            W2T + (long)l * 128 * 128, edge_b2 + (long)l * HIDDEN);
        const unsigned short* w1next = (l + 1 < NLAYERS) ? (W1T + (long)(l + 1) * 384 * 128) : nullptr;
        node_layer_mfma<<<(NNODES + 63) / 64, 512, 0, stream>>>(
            x, sums, deg,
            N1T + (long)l * 256 * 128, node_b1 + (long)l * HIDDEN,
            N2T + (long)l * 128 * 128, node_b2 + (long)l * HIDDEN,
            w1next, Xa, Xb);
    }

    decode_kernel<<<(NNODES * 64 + 255) / 256, 256, 0, stream>>>(x, dec_w, dec_b, out);
}

// Round 9
// 1440.513 us; speedup vs baseline: 1.1282x; 1.0403x over previous
//
#include <hip/hip_runtime.h>
#include <cstdint>

#define HIDDEN  128
#define NLAYERS 6
#define NNODES  50000
#define NEDGES  640000

typedef short short8 __attribute__((ext_vector_type(8)));
typedef float f32x4  __attribute__((ext_vector_type(4)));
typedef unsigned int   u32x4 __attribute__((ext_vector_type(4)));
typedef unsigned int   u32x2 __attribute__((ext_vector_type(2)));

// ---- bf16 <-> f32 helpers -------------------------------------------------
__device__ __forceinline__ float bf2f(unsigned short u) {
    return __uint_as_float(((unsigned int)u) << 16);
}
__device__ __forceinline__ unsigned short f2bf(float f) {
    unsigned int u = __float_as_uint(f);
    unsigned int r = u + 0x7FFFu + ((u >> 16) & 1u);
    return (unsigned short)(r >> 16);
}
// HW packed conversion: v_cvt_pk_bf16_f32 (RNE) == f2bf(a) | f2bf(b)<<16.
__device__ __forceinline__ unsigned int pack2(float a, float b) {
    unsigned int r;
    asm("v_cvt_pk_bf16_f32 %0, %1, %2" : "=v"(r) : "v"(a), "v"(b));
    return r;
}
__device__ __forceinline__ void unpack8u(u32x4 v, float* f) {
    f[0] = bf2f((unsigned short)(v.x & 0xffff)); f[1] = bf2f((unsigned short)(v.x >> 16));
    f[2] = bf2f((unsigned short)(v.y & 0xffff)); f[3] = bf2f((unsigned short)(v.y >> 16));
    f[4] = bf2f((unsigned short)(v.z & 0xffff)); f[5] = bf2f((unsigned short)(v.z >> 16));
    f[6] = bf2f((unsigned short)(v.w & 0xffff)); f[7] = bf2f((unsigned short)(v.w >> 16));
}

// ---- barrier that drains ONLY lgkmcnt (LDS); prefetched global loads stay
//      in flight across it. Cross-wave deps here flow through LDS only.
__device__ __forceinline__ void barrier_lgkm() {
    asm volatile("s_waitcnt lgkmcnt(0)" ::: "memory");
    __builtin_amdgcn_s_barrier();
    __builtin_amdgcn_sched_barrier(0);
}

// ---------------------------------------------------------------------------
// Index dtype detection + canonicalization
// ---------------------------------------------------------------------------
__global__ void detect_kernel(const int* __restrict__ ei, int* __restrict__ flag)
{
    int lane = threadIdx.x;
    int v = ei[2 * lane + 1];
    unsigned long long b = __ballot(v != 0);
    if (lane == 0) *flag = (b != 0ULL) ? 1 : 0;
}

__global__ void normidx_kernel(const int* __restrict__ ei, const int* __restrict__ flag,
                               int* __restrict__ s32, int* __restrict__ d32)
{
    int e = blockIdx.x * blockDim.x + threadIdx.x;
    if (e >= NEDGES) return;
    int s, d;
    if (*flag) { s = ei[e]; d = ei[NEDGES + e]; }
    else       { s = ei[2 * e]; d = ei[2 * (NEDGES + e)]; }
    s32[e] = min(max(s, 0), NNODES - 1);
    d32[e] = min(max(d, 0), NNODES - 1);
}

__global__ void degree_kernel(const int* __restrict__ dst, int* __restrict__ deg)
{
    int e = blockIdx.x * blockDim.x + threadIdx.x;
    if (e < NEDGES) atomicAdd(&deg[dst[e]], 1);
}

// ---------------------------------------------------------------------------
// Exclusive scan over deg[0..NNODES) -> off, cursor. One 1024-thread block.
// ---------------------------------------------------------------------------
#define SCAN_T 1024
__global__ void scan_kernel(const int* __restrict__ deg, int* __restrict__ off,
                            int* __restrict__ cursor)
{
    __shared__ int part[SCAN_T];
    const int t = threadIdx.x;
    const int CH = (NNODES + SCAN_T - 1) / SCAN_T;
    const int base = t * CH;
    int s = 0;
    for (int i = 0; i < CH; ++i) {
        int idx = base + i;
        if (idx < NNODES) s += deg[idx];
    }
    part[t] = s;
    __syncthreads();
    for (int d = 1; d < SCAN_T; d <<= 1) {
        int v = (t >= d) ? part[t - d] : 0;
        __syncthreads();
        part[t] += v;
        __syncthreads();
    }
    int run = (t == 0) ? 0 : part[t - 1];
    for (int i = 0; i < CH; ++i) {
        int idx = base + i;
        if (idx < NNODES) {
            off[idx] = run;
            cursor[idx] = run;
            run += deg[idx];
        }
    }
    if (t == SCAN_T - 1) off[NNODES] = run;
}

__global__ void scatter_kernel(const int* __restrict__ s32, const int* __restrict__ d32,
                               int* __restrict__ cursor,
                               int* __restrict__ sp, int* __restrict__ dp, int* __restrict__ ep)
{
    int e = blockIdx.x * blockDim.x + threadIdx.x;
    if (e >= NEDGES) return;
    int d = d32[e];
    int p = atomicAdd(&cursor[d], 1);
    sp[p] = s32[e];
    dp[p] = d;
    ep[p] = e;
}

// ---------------------------------------------------------------------------
// Weight transpose+convert: W [L][K][N] fp32 -> WT [L][N][K] bf16
// ---------------------------------------------------------------------------
__global__ void transpose_kernel(const float* __restrict__ W, unsigned short* __restrict__ WT,
                                 int K, int N, int L)
{
    long idx = (long)blockIdx.x * 256 + threadIdx.x;
    long tot = (long)L * K * N;
    if (idx >= tot) return;
    int kn = (int)(idx % ((long)K * N));
    int l  = (int)(idx / ((long)K * N));
    int k = kn / N;
    int n = kn % N;
    WT[(long)l * K * N + (long)n * K + k] = f2bf(W[idx]);
}

// ---------------------------------------------------------------------------
// Encoder into permuted layout: ef[p] = enc(ea[ep[p]])
// ---------------------------------------------------------------------------
__global__ void encode_kernel(const float* __restrict__ ea,
                              const float* __restrict__ w,
                              const float* __restrict__ b,
                              const int* __restrict__ ep,
                              unsigned short* __restrict__ ef)
{
    int idx = blockIdx.x * blockDim.x + threadIdx.x;
    int p = idx >> 5;
    if (p >= NEDGES) return;
    int e = ep[p];
    int j = (idx & 31) << 2;
    float a0 = ea[e * 3 + 0], a1 = ea[e * 3 + 1], a2 = ea[e * 3 + 2];
    float4 w0 = *(const float4*)(w + 0 * HIDDEN + j);
    float4 w1 = *(const float4*)(w + 1 * HIDDEN + j);
    float4 w2 = *(const float4*)(w + 2 * HIDDEN + j);
    float4 bb = *(const float4*)(b + j);
    ushort4 o;
    o.x = f2bf(fmaf(a0, w0.x, fmaf(a1, w1.x, fmaf(a2, w2.x, bb.x))));
    o.y = f2bf(fmaf(a0, w0.y, fmaf(a1, w1.y, fmaf(a2, w2.y, bb.y))));
    o.z = f2bf(fmaf(a0, w0.z, fmaf(a1, w1.z, fmaf(a2, w2.z, bb.z))));
    o.w = f2bf(fmaf(a0, w0.w, fmaf(a1, w1.w, fmaf(a2, w2.w, bb.w))));
    *(ushort4*)(ef + (long)p * HIDDEN + j) = o;
}

// ---------------------------------------------------------------------------
// MFMA edge layer — round-6 A-DIRECT structure + layer-boundary flags:
//   flags bit0 (FIRST): Xa/Xb are all-zero -> skip the gather phase; write
//                       H = relu(pre + b1) directly in the C-layout epilogue.
//   flags bit1 (LAST):  ef_new is never consumed -> skip the 164 MB ef store.
// Both are bit-identical transformations (adding 0.0 / dead-store removal).
// ---------------------------------------------------------------------------
__global__ __launch_bounds__(256, 3)
void edge_layer_mfma(const unsigned short* __restrict__ Xa,   // [N][128] bf16
                     const unsigned short* __restrict__ Xb,   // [N][128] bf16
                     unsigned short* __restrict__ ef,
                     float* __restrict__ sums,
                     const int* __restrict__ sp,
                     const int* __restrict__ dp,
                     const unsigned short* __restrict__ W1T,  // [128][384] bf16; W1c at k+256
                     const float* __restrict__ b1,
                     const unsigned short* __restrict__ W2T,  // [128][128] bf16
                     const float* __restrict__ b2,
                     const int flags)
{
    __shared__ __align__(16) unsigned char buf[45056];
    unsigned short* Hs = (unsigned short*)buf;               // 128 x 136
    unsigned short* Bs = (unsigned short*)(buf + 34816);     // 128 x 40
    __shared__ int dv[128];
    __shared__ int sv[128];

    const int tid = threadIdx.x;
    // XCD-chunked swizzle: grid = 5000 (= 8 x 625). Each XCD gets a contiguous
    // edge (= dst) range -> sums atomic lines stay in its private L2.
    const int nwg = (int)gridDim.x;
    const int bid = (int)blockIdx.x;
    const int sb  = (bid & 7) * (nwg >> 3) + (bid >> 3);
    const long eb = (long)sb * 128;

    if (tid < 128) dv[tid]       = dp[eb + tid];
    else           sv[tid - 128] = sp[eb + tid - 128];

    const int lane = tid & 63;
    const int wv   = tid >> 6;
    const int mn   = lane & 15;
    const int q    = lane >> 4;
    const int bn   = tid >> 1;
    const int bk   = (tid & 1) << 4;

    // W chunk-0 prefetch FIRST so its vmcnt wait doesn't drain the A loads.
    u32x4 pw0, pw1;
    {
        const unsigned short* wp = W1T + (long)bn * 384 + 256 + bk;
        pw0 = *(const u32x4*)wp;
        pw1 = *(const u32x4*)(wp + 8);
    }

    // All GEMM1 A-fragments direct from global; they ARE the ef_old registers
    // kept for the residual. 16 x 16B loads in flight.
    short8 efold0[4], efold1[4];
    {
        const unsigned short* a0 = ef + (eb + wv * 32 + mn) * HIDDEN + (q << 3);
        const unsigned short* a1 = a0 + 16 * HIDDEN;
#pragma unroll
        for (int c = 0; c < 4; ++c) {
            efold0[c] = *(const short8*)(a0 + (c << 5));
            efold1[c] = *(const short8*)(a1 + (c << 5));
        }
    }

    f32x4 acc[2][8];
#pragma unroll
    for (int h = 0; h < 2; ++h)
#pragma unroll
        for (int t = 0; t < 8; ++t) acc[h][t] = (f32x4)0.0f;

    for (int c = 0; c < 4; ++c) {
        *(u32x4*)&Bs[bn * 40 + bk]     = pw0;
        *(u32x4*)&Bs[bn * 40 + bk + 8] = pw1;
        barrier_lgkm();
        if (c + 1 < 4) {
            const unsigned short* wp = W1T + (long)bn * 384 + 256 + ((c + 1) << 5) + bk;
            pw0 = *(const u32x4*)wp;
            pw1 = *(const u32x4*)(wp + 8);
        }
        short8 af0 = efold0[c];
        short8 af1 = efold1[c];
#pragma unroll
        for (int nt = 0; nt < 8; ++nt) {
            short8 bf = *(short8*)&Bs[(nt * 16 + mn) * 40 + (q << 3)];
            acc[0][nt] = __builtin_amdgcn_mfma_f32_16x16x32_bf16(af0, bf, acc[0][nt], 0, 0, 0);
            acc[1][nt] = __builtin_amdgcn_mfma_f32_16x16x32_bf16(af1, bf, acc[1][nt], 0, 0, 0);
        }
        barrier_lgkm();
    }

    if (flags & 1) {
        // ---- FIRST layer: Xa/Xb == 0 -> H = relu(pre + b1) directly ----
#pragma unroll
        for (int h = 0; h < 2; ++h)
#pragma unroll
            for (int nt = 0; nt < 8; ++nt) {
                float b1v = b1[nt * 16 + mn];
#pragma unroll
                for (int r = 0; r < 4; r += 2) {
                    float h0 = fmaxf(acc[h][nt][r]     + b1v, 0.0f);
                    float h1 = fmaxf(acc[h][nt][r + 1] + b1v, 0.0f);
                    unsigned int p = pack2(h0, h1);
                    Hs[(wv * 32 + h * 16 + q * 4 + r)     * 136 + nt * 16 + mn] = (unsigned short)p;
                    Hs[(wv * 32 + h * 16 + q * 4 + r + 1) * 136 + nt * 16 + mn] = (unsigned short)(p >> 16);
                }
            }
    } else {
        // ---- pre -> Hs (C-layout, own wave band), packed conversion ----
#pragma unroll
        for (int h = 0; h < 2; ++h)
#pragma unroll
            for (int nt = 0; nt < 8; ++nt)
#pragma unroll
                for (int r = 0; r < 4; r += 2) {
                    unsigned int p = pack2(acc[h][nt][r], acc[h][nt][r + 1]);
                    Hs[(wv * 32 + h * 16 + q * 4 + r)     * 136 + nt * 16 + mn] = (unsigned short)p;
                    Hs[(wv * 32 + h * 16 + q * 4 + r + 1) * 136 + nt * 16 + mn] = (unsigned short)(p >> 16);
                }

        // ---- H = relu(pre + Xa[dst] + Xb[src] + b1), row-major gather ----
        {
            const int row  = wv * 32 + (lane >> 1);
            const int ch   = (lane & 1) << 6;
            const unsigned short* xap = Xa + (long)dv[row] * HIDDEN + ch;
            const unsigned short* xbp = Xb + (long)sv[row] * HIDDEN + ch;
            unsigned short* hp = &Hs[row * 136 + ch];
#pragma unroll
            for (int i = 0; i < 8; ++i) {
                u32x4 va = *(const u32x4*)(xap + (i << 3));
                u32x4 vb = *(const u32x4*)(xbp + (i << 3));
                u32x4 vp = *(u32x4*)(hp + (i << 3));
                float fa[8], fb[8], fp[8];
                unpack8u(va, fa); unpack8u(vb, fb); unpack8u(vp, fp);
                const float* bp = b1 + ch + (i << 3);
                u32x4 nw;
                float h0 = fmaxf(fp[0] + fa[0] + fb[0] + bp[0], 0.0f);
                float h1 = fmaxf(fp[1] + fa[1] + fb[1] + bp[1], 0.0f);
                float h2 = fmaxf(fp[2] + fa[2] + fb[2] + bp[2], 0.0f);
                float h3 = fmaxf(fp[3] + fa[3] + fb[3] + bp[3], 0.0f);
                float h4 = fmaxf(fp[4] + fa[4] + fb[4] + bp[4], 0.0f);
                float h5 = fmaxf(fp[5] + fa[5] + fb[5] + bp[5], 0.0f);
                float h6 = fmaxf(fp[6] + fa[6] + fb[6] + bp[6], 0.0f);
                float h7 = fmaxf(fp[7] + fa[7] + fb[7] + bp[7], 0.0f);
                nw.x = pack2(h0, h1); nw.y = pack2(h2, h3);
                nw.z = pack2(h4, h5); nw.w = pack2(h6, h7);
                *(u32x4*)(hp + (i << 3)) = nw;
            }
        }
    }
    // No barrier: GEMM2 A-frags read only this wave's band (DS wave-ordered).

    f32x4 acc2[2][8];
#pragma unroll
    for (int h = 0; h < 2; ++h)
#pragma unroll
        for (int t = 0; t < 8; ++t) acc2[h][t] = (f32x4)0.0f;
    {
        const unsigned short* wp = W2T + (long)bn * 128 + bk;
        pw0 = *(const u32x4*)wp;
        pw1 = *(const u32x4*)(wp + 8);
    }
    for (int c = 0; c < 4; ++c) {
        *(u32x4*)&Bs[bn * 40 + bk]     = pw0;
        *(u32x4*)&Bs[bn * 40 + bk + 8] = pw1;
        barrier_lgkm();
        if (c + 1 < 4) {
            const unsigned short* wp = W2T + (long)bn * 128 + ((c + 1) << 5) + bk;
            pw0 = *(const u32x4*)wp;
            pw1 = *(const u32x4*)(wp + 8);
        }
        short8 af0 = *(short8*)&Hs[(wv * 32 + mn) * 136 + (c << 5) + (q << 3)];
        short8 af1 = *(short8*)&Hs[(wv * 32 + 16 + mn) * 136 + (c << 5) + (q << 3)];
#pragma unroll
        for (int nt = 0; nt < 8; ++nt) {
            short8 bf = *(short8*)&Bs[(nt * 16 + mn) * 40 + (q << 3)];
            acc2[0][nt] = __builtin_amdgcn_mfma_f32_16x16x32_bf16(af0, bf, acc2[0][nt], 0, 0, 0);
            acc2[1][nt] = __builtin_amdgcn_mfma_f32_16x16x32_bf16(af1, bf, acc2[1][nt], 0, 0, 0);
        }
        barrier_lgkm();
    }

    // ---- m = acc2 + b2 -> Hs (C-layout, own band), packed conversion ----
#pragma unroll
    for (int h = 0; h < 2; ++h)
#pragma unroll
        for (int nt = 0; nt < 8; ++nt) {
            float b2v = b2[nt * 16 + mn];
#pragma unroll
            for (int r = 0; r < 4; r += 2) {
                unsigned int p = pack2(acc2[h][nt][r] + b2v, acc2[h][nt][r + 1] + b2v);
                Hs[(wv * 32 + h * 16 + q * 4 + r)     * 136 + nt * 16 + mn] = (unsigned short)p;
                Hs[(wv * 32 + h * 16 + q * 4 + r + 1) * 136 + nt * 16 + mn] = (unsigned short)(p >> 16);
            }
        }

    // ---- ef_new = ef_old(regs) + m (skipped in LAST layer: dead store) ----
    if (!(flags & 2)) {
#pragma unroll
        for (int h = 0; h < 2; ++h) {
            const int row = wv * 32 + h * 16 + mn;
            unsigned short* ep_ = ef + (eb + row) * HIDDEN + (q << 3);
#pragma unroll
            for (int c = 0; c < 4; ++c) {
                u32x4 mh = *(u32x4*)&Hs[row * 136 + (c << 5) + (q << 3)];
                float m[8], e[8];
                unpack8u(mh, m);
                short8 eo = h ? efold1[c] : efold0[c];
                u32x4 eu = *(u32x4*)&eo;
                unpack8u(eu, e);
                u32x4 nw;
                nw.x = pack2(e[0] + m[0], e[1] + m[1]);
                nw.y = pack2(e[2] + m[2], e[3] + m[3]);
                nw.z = pack2(e[4] + m[4], e[5] + m[5]);
                nw.w = pack2(e[6] + m[6], e[7] + m[7]);
                *(u32x4*)(ep_ + (c << 5)) = nw;
            }
        }
    }

    // ---- segmented reduction by dst-run (own band rows, barrier-free) ----
    {
        const int cp = (tid & 63) << 1;
        const int qr = tid >> 6;
        float s0 = 0.0f, s1 = 0.0f;
        int cur = dv[qr * 32];
        for (int r = 0; r < 32; ++r) {
            const int row = qr * 32 + r;
            const int d = dv[row];
            if (d != cur) {
                atomicAdd(&sums[(long)cur * HIDDEN + cp], s0);
                atomicAdd(&sums[(long)cur * HIDDEN + cp + 1], s1);
                s0 = 0.0f; s1 = 0.0f;
                cur = d;
            }
            unsigned int u = *(unsigned int*)&Hs[row * 136 + cp];
            s0 += bf2f((unsigned short)(u & 0xffff));
            s1 += bf2f((unsigned short)(u >> 16));
        }
        atomicAdd(&sums[(long)cur * HIDDEN + cp], s0);
        atomicAdd(&sums[(long)cur * HIDDEN + cp + 1], s1);
    }
}

// ---------------------------------------------------------------------------
// MFMA node layer — round-8 8-WAVE OUTPUT-SPLIT variant; sums-zeroing now
// gated on W1Tn (last layer has no successor edge layer -> dead writes).
// ---------------------------------------------------------------------------
__global__ __launch_bounds__(512, 6)
void node_layer_mfma(float* __restrict__ x,
                     float* __restrict__ sums,
                     const int* __restrict__ deg,
                     const unsigned short* __restrict__ N1T,  // [128][256] bf16
                     const float* __restrict__ b1,
                     const unsigned short* __restrict__ N2T,  // [128][128] bf16
                     const float* __restrict__ b2,
                     const unsigned short* __restrict__ W1Tn, // [128][384] next layer (or null)
                     unsigned short* __restrict__ Xa,
                     unsigned short* __restrict__ Xb)
{
    // 0     .. 17408 : Hs (64 x 136) / As (64 x 40) aliased
    // 17408 .. 27648 : Bs (128 x 40)
    __shared__ __align__(16) unsigned char nbuf[27648];
    unsigned short* As = (unsigned short*)nbuf;
    unsigned short* Hs = (unsigned short*)nbuf;
    unsigned short* Bs = (unsigned short*)(nbuf + 17408);
    __shared__ float cInv[64];

    const int tid = threadIdx.x;
    const long n0 = (long)blockIdx.x * 64;
    if (tid < 64) {
        long n = n0 + tid;
        cInv[tid] = (n < NNODES) ? 1.0f / fmaxf((float)deg[n], 1.0f) : 0.0f;
    }

    const int lane = tid & 63;
    const int wv   = tid >> 6;        // 0..7
    const int wb   = wv & 3;          // row band: rows [wb*16, wb*16+16)
    const int nh   = wv >> 2;         // nt half: output cols [nh*64, nh*64+64)
    const int mn   = lane & 15;
    const int q    = lane >> 4;
    const int srow = tid >> 3;        // 0..63  (A-staging / zeroing row)
    const int ss   = tid & 7;         // staging seg: 4 floats
    const int bn   = tid >> 2;        // 0..127 (B-staging row)
    const int bk   = (tid & 3) << 3;  // B-staging col offset (shorts)

    long nr = n0 + srow;
    if (nr >= NNODES) nr = NNODES - 1;

    barrier_lgkm();   // cInv visible to all waves

    f32x4 acc[4];
#pragma unroll
    for (int t = 0; t < 4; ++t) acc[t] = (f32x4)0.0f;

    float4 pa;
    u32x4 pb;
    {
        const float* spx = x + nr * HIDDEN + (ss << 2);
        pa = *(const float4*)spx;
        const unsigned short* wp = N1T + (long)bn * 256 + bk;
        pb = *(const u32x4*)wp;
    }
    float scCur = 1.0f;
    for (int c = 0; c < 8; ++c) {
        {
            u32x2 w;
            w.x = pack2(pa.x * scCur, pa.y * scCur);
            w.y = pack2(pa.z * scCur, pa.w * scCur);
            *(u32x2*)&As[srow * 40 + (ss << 2)] = w;
        }
        *(u32x4*)&Bs[bn * 40 + bk] = pb;
        barrier_lgkm();
        if (c + 1 < 8) {
            const int cn = c + 1;
            const float* base = (cn < 4) ? x : sums;
            scCur = (cn < 4) ? 1.0f : cInv[srow];
            const float* spx = base + nr * HIDDEN + ((cn & 3) << 5) + (ss << 2);
            pa = *(const float4*)spx;
            const unsigned short* wp = N1T + (long)bn * 256 + (cn << 5) + bk;
            pb = *(const u32x4*)wp;
        }
        short8 af = *(short8*)&As[(wb * 16 + mn) * 40 + (q << 3)];
#pragma unroll
        for (int nt = 0; nt < 4; ++nt) {
            const int ntp = nh * 4 + nt;
            short8 bf = *(short8*)&Bs[(ntp * 16 + mn) * 40 + (q << 3)];
            acc[nt] = __builtin_amdgcn_mfma_f32_16x16x32_bf16(af, bf, acc[nt], 0, 0, 0);
        }
        barrier_lgkm();
    }
    // As reads done (final barrier above) -> Hs alias safe.

    // zero own sums rows for the NEXT edge layer (dead in last layer).
    if (W1Tn) {
        long row = n0 + srow;
        if (row < NNODES) {
            float4 z = make_float4(0.f, 0.f, 0.f, 0.f);
            float* p = sums + row * HIDDEN + (ss << 4);
#pragma unroll
            for (int i = 0; i < 4; ++i) ((float4*)p)[i] = z;
        }
    }

    // ---- H = relu(acc + b1) -> Hs (own rowband x nt-half quadrant) ----
#pragma unroll
    for (int nt = 0; nt < 4; ++nt) {
        const int ntp = nh * 4 + nt;
        float b1v = b1[ntp * 16 + mn];
#pragma unroll
        for (int r = 0; r < 4; r += 2) {
            float h0 = fmaxf(acc[nt][r]     + b1v, 0.0f);
            float h1 = fmaxf(acc[nt][r + 1] + b1v, 0.0f);
            unsigned int p = pack2(h0, h1);
            Hs[(wb * 16 + q * 4 + r)     * 136 + ntp * 16 + mn] = (unsigned short)p;
            Hs[(wb * 16 + q * 4 + r + 1) * 136 + ntp * 16 + mn] = (unsigned short)(p >> 16);
        }
    }

    f32x4 acc2[4];
#pragma unroll
    for (int t = 0; t < 4; ++t) acc2[t] = (f32x4)0.0f;
    {
        const unsigned short* wp = N2T + (long)bn * 128 + bk;
        pb = *(const u32x4*)wp;
    }
    for (int c = 0; c < 4; ++c) {
        *(u32x4*)&Bs[bn * 40 + bk] = pb;
        barrier_lgkm();   // also syncs partner wave's H quadrant writes
        if (c + 1 < 4) {
            const unsigned short* wp = N2T + (long)bn * 128 + ((c + 1) << 5) + bk;
            pb = *(const u32x4*)wp;
        }
        short8 af = *(short8*)&Hs[(wb * 16 + mn) * 136 + (c << 5) + (q << 3)];
#pragma unroll
        for (int nt = 0; nt < 4; ++nt) {
            const int ntp = nh * 4 + nt;
            short8 bf = *(short8*)&Bs[(ntp * 16 + mn) * 40 + (q << 3)];
            acc2[nt] = __builtin_amdgcn_mfma_f32_16x16x32_bf16(af, bf, acc2[nt], 0, 0, 0);
        }
        barrier_lgkm();
    }

    // ---- xnew = x + acc2 + b2 (exact fp32); stage xnew bf16 into Hs ----
#pragma unroll
    for (int nt = 0; nt < 4; ++nt) {
        const int ntp = nh * 4 + nt;
        float b2v = b2[ntp * 16 + mn];
        float xns[4];
#pragma unroll
        for (int r = 0; r < 4; ++r) {
            long row = n0 + wb * 16 + q * 4 + r;
            float xn = 0.0f;
            if (row < NNODES) {
                float* p = x + row * HIDDEN + ntp * 16 + mn;
                xn = *p + acc2[nt][r] + b2v;
                *p = xn;
            }
            xns[r] = xn;
        }
        unsigned int p0 = pack2(xns[0], xns[1]);
        unsigned int p1 = pack2(xns[2], xns[3]);
        Hs[(wb * 16 + q * 4 + 0) * 136 + ntp * 16 + mn] = (unsigned short)p0;
        Hs[(wb * 16 + q * 4 + 1) * 136 + ntp * 16 + mn] = (unsigned short)(p0 >> 16);
        Hs[(wb * 16 + q * 4 + 2) * 136 + ntp * 16 + mn] = (unsigned short)p1;
        Hs[(wb * 16 + q * 4 + 3) * 136 + ntp * 16 + mn] = (unsigned short)(p1 >> 16);
    }

    // ---- Xa/Xb for next layer: xnew @ W1a / W1b ----
    if (W1Tn) {
#pragma unroll
        for (int half = 0; half < 2; ++half) {
            f32x4 accN[4];
#pragma unroll
            for (int t = 0; t < 4; ++t) accN[t] = (f32x4)0.0f;
            const int kbase = half << 7;
            {
                const unsigned short* wp = W1Tn + (long)bn * 384 + kbase + bk;
                pb = *(const u32x4*)wp;
            }
            for (int c = 0; c < 4; ++c) {
                *(u32x4*)&Bs[bn * 40 + bk] = pb;
                barrier_lgkm();   // also syncs partner wave's xnew Hs writes
                if (c + 1 < 4) {
                    const unsigned short* wp = W1Tn + (long)bn * 384 + kbase + ((c + 1) << 5) + bk;
                    pb = *(const u32x4*)wp;
                }
                short8 af = *(short8*)&Hs[(wb * 16 + mn) * 136 + (c << 5) + (q << 3)];
#pragma unroll
                for (int nt = 0; nt < 4; ++nt) {
                    const int ntp = nh * 4 + nt;
                    short8 bf = *(short8*)&Bs[(ntp * 16 + mn) * 40 + (q << 3)];
                    accN[nt] = __builtin_amdgcn_mfma_f32_16x16x32_bf16(af, bf, accN[nt], 0, 0, 0);
                }
                barrier_lgkm();
            }
            unsigned short* Xout = half ? Xb : Xa;
#pragma unroll
            for (int nt = 0; nt < 4; ++nt) {
                const int ntp = nh * 4 + nt;
#pragma unroll
                for (int r = 0; r < 4; r += 2) {
                    unsigned int p = pack2(accN[nt][r], accN[nt][r + 1]);
                    long row0 = n0 + wb * 16 + q * 4 + r;
                    if (row0 < NNODES)
                        Xout[row0 * HIDDEN + ntp * 16 + mn] = (unsigned short)p;
                    if (row0 + 1 < NNODES)
                        Xout[(row0 + 1) * HIDDEN + ntp * 16 + mn] = (unsigned short)(p >> 16);
                }
            }
        }
    }
}

// ---------------------------------------------------------------------------
// Decoder + row L2-normalize (one wave per node)
// ---------------------------------------------------------------------------
__global__ void decode_kernel(const float* __restrict__ x,
                              const float* __restrict__ w,
                              const float* __restrict__ b,
                              float* __restrict__ out)
{
    int gid = blockIdx.x * blockDim.x + threadIdx.x;
    int node = gid >> 6;
    int lane = threadIdx.x & 63;
    if (node >= NNODES) return;
    float a0 = 0.f, a1 = 0.f, a2 = 0.f;
#pragma unroll
    for (int k = lane; k < HIDDEN; k += 64) {
        float xv = x[(long)node * HIDDEN + k];
        a0 = fmaf(xv, w[k * 3 + 0], a0);
        a1 = fmaf(xv, w[k * 3 + 1], a1);
        a2 = fmaf(xv, w[k * 3 + 2], a2);
    }
#pragma unroll
    for (int off = 32; off > 0; off >>= 1) {
        a0 += __shfl_down(a0, off);
        a1 += __shfl_down(a1, off);
        a2 += __shfl_down(a2, off);
    }
    if (lane == 0) {
        a0 += b[0]; a1 += b[1]; a2 += b[2];
        float nrm = sqrtf(a0 * a0 + a1 * a1 + a2 * a2);
        float inv = 1.0f / fmaxf(nrm, 1e-12f);
        out[(long)node * 3 + 0] = a0 * inv;
        out[(long)node * 3 + 1] = a1 * inv;
        out[(long)node * 3 + 2] = a2 * inv;
    }
}

// ---------------------------------------------------------------------------
extern "C" void kernel_launch(void* const* d_in, const int* in_sizes, int n_in,
                              void* d_out, int out_size, void* d_ws, size_t ws_size,
                              hipStream_t stream)
{
    const float* edge_attr = (const float*)d_in[1];
    const int*   ei        = (const int*)d_in[2];
    const float* enc_w     = (const float*)d_in[3];
    const float* enc_b     = (const float*)d_in[4];
    const float* dec_w     = (const float*)d_in[5];
    const float* dec_b     = (const float*)d_in[6];
    const float* edge_w1   = (const float*)d_in[7];
    const float* edge_b1   = (const float*)d_in[8];
    const float* edge_w2   = (const float*)d_in[9];
    const float* edge_b2   = (const float*)d_in[10];
    const float* node_w1   = (const float*)d_in[11];
    const float* node_b1   = (const float*)d_in[12];
    const float* node_w2   = (const float*)d_in[13];
    const float* node_b2   = (const float*)d_in[14];

    // workspace layout (bytes), 16B-aligned, total ~255.4 MB
    char* ws = (char*)d_ws;
    unsigned short* ef  = (unsigned short*)(ws);                  // 163,840,000
    float* x      = (float*)(ws + 163840000L);                    //  25,600,000
    float* sums   = (float*)(ws + 189440000L);                    //  25,600,000
    int*   src32  = (int*)  (ws + 215040000L);                    //   2,560,000
    int*   dst32  = (int*)  (ws + 217600000L);                    //   2,560,000
    int*   sp     = (int*)  (ws + 220160000L);                    //   2,560,000
    int*   dp     = (int*)  (ws + 222720000L);                    //   2,560,000
    int*   eperm  = (int*)  (ws + 225280000L);                    //   2,560,000
    int*   deg    = (int*)  (ws + 227840000L);                    //     200,704
    int*   off    = (int*)  (ws + 228040704L);                    //     200,704
    int*   cursor = (int*)  (ws + 228241408L);                    //     200,704
    int*   flag   = (int*)  (ws + 228442112L);                    //          64
    unsigned short* W1T = (unsigned short*)(ws + 228442176L);     //     589,824
    unsigned short* W2T = (unsigned short*)(ws + 229032000L);     //     196,608
    unsigned short* N1T = (unsigned short*)(ws + 229228608L);     //     393,216
    unsigned short* N2T = (unsigned short*)(ws + 229621824L);     //     196,608
    unsigned short* Xa  = (unsigned short*)(ws + 229818432L);     //  12,800,000
    unsigned short* Xb  = (unsigned short*)(ws + 242618432L);     //  12,800,000
    // end: 255,418,432

    float* out = (float*)d_out;

    hipMemsetAsync(x, 0, (size_t)NNODES * HIDDEN * sizeof(float), stream);
    hipMemsetAsync(sums, 0, (size_t)NNODES * HIDDEN * sizeof(float), stream);
    hipMemsetAsync(deg, 0, 200704, stream);
    // Xa/Xb memset no longer needed: layer-0 edge skips the gather phase.

    detect_kernel<<<1, 64, 0, stream>>>(ei, flag);
    normidx_kernel<<<(NEDGES + 255) / 256, 256, 0, stream>>>(ei, flag, src32, dst32);
    degree_kernel<<<(NEDGES + 255) / 256, 256, 0, stream>>>(dst32, deg);
    scan_kernel<<<1, SCAN_T, 0, stream>>>(deg, off, cursor);
    scatter_kernel<<<(NEDGES + 255) / 256, 256, 0, stream>>>(src32, dst32, cursor, sp, dp, eperm);
    encode_kernel<<<(NEDGES * 32 + 255) / 256, 256, 0, stream>>>(edge_attr, enc_w, enc_b, eperm, ef);

    transpose_kernel<<<(6 * 384 * 128 + 255) / 256, 256, 0, stream>>>(edge_w1, W1T, 384, 128, 6);
    transpose_kernel<<<(6 * 128 * 128 + 255) / 256, 256, 0, stream>>>(edge_w2, W2T, 128, 128, 6);
    transpose_kernel<<<(6 * 256 * 128 + 255) / 256, 256, 0, stream>>>(node_w1, N1T, 256, 128, 6);
    transpose_kernel<<<(6 * 128 * 128 + 255) / 256, 256, 0, stream>>>(node_w2, N2T, 128, 128, 6);

    for (int l = 0; l < NLAYERS; ++l) {
        const int flags = (l == 0 ? 1 : 0) | (l == NLAYERS - 1 ? 2 : 0);
        edge_layer_mfma<<<NEDGES / 128, 256, 0, stream>>>(
            Xa, Xb, ef, sums, sp, dp,
            W1T + (long)l * 384 * 128, edge_b1 + (long)l * HIDDEN,
            W2T + (long)l * 128 * 128, edge_b2 + (long)l * HIDDEN, flags);
        const unsigned short* w1next = (l + 1 < NLAYERS) ? (W1T + (long)(l + 1) * 384 * 128) : nullptr;
        node_layer_mfma<<<(NNODES + 63) / 64, 512, 0, stream>>>(
            x, sums, deg,
            N1T + (long)l * 256 * 128, node_b1 + (long)l * HIDDEN,
            N2T + (long)l * 128 * 128, node_b2 + (long)l * HIDDEN,
            w1next, Xa, Xb);
    }

    decode_kernel<<<(NNODES * 64 + 255) / 256, 256, 0, stream>>>(x, dec_w, dec_b, out);
}